// Round 3
// baseline (376.772 us; speedup 1.0000x reference)
//
#include <hip/hip_runtime.h>
#include <math.h>

// Problem constants
static constexpr int TT = 8192;          // sequence length
static constexpr int LFULL = 8196;       // Lmax (8194) + pad to mult of 3 (2)
static constexpr int BSTRIDE = LFULL + 2; // bounds per-batch stride (lf+1 for lf in [-1, LFULL])

// d_out layout (floats, concatenated in reference return order)
static constexpr size_t XE_OFF   = 0;                       // [16][256][8196]
static constexpr size_t LENS_OFF = (size_t)16*256*LFULL;
static constexpr size_t BM_OFF   = LENS_OFF + 16;           // bmoves [16][8192]
static constexpr size_t WT_OFF   = BM_OFF + (size_t)16*TT;  // weights [16][8192]

// ws layout (floats). bnd overlays u (u is dead after k_conv2; same-stream ordering).
static constexpr size_t U_OFF     = 0;                        // [16][32][8192]
static constexpr size_t V_OFF     = U_OFF + (size_t)16*32*TT; // [16][32][8192]
static constexpr size_t MOVES_OFF = V_OFF + (size_t)16*32*TT;
static constexpr size_t C1_OFF    = MOVES_OFF + (size_t)16*TT;
static constexpr size_t C2_OFF    = C1_OFF + (size_t)16*TT;
static constexpr size_t BND_OFF   = U_OFF;                    // int[16][BSTRIDE], 525 KB << 16.8 MB

__device__ __forceinline__ float sig_(float z) { return 1.0f / (1.0f + __expf(-z)); }

// ---------------- Kernel 1a: conv1 (2->32, k=31, pad15) + BN(1e-5) + swish -> u ----------------
__global__ __launch_bounds__(256) void k_conv1(
    const float* __restrict__ x,
    const float* __restrict__ p1w, const float* __restrict__ p1b,
    const float* __restrict__ g1, const float* __restrict__ b1,
    const float* __restrict__ m1, const float* __restrict__ v1,
    float* __restrict__ u)
{
    __shared__ float xin[2 * 320];   // [ci][xl], xl -> t0-15+xl, valid xl<286
    __shared__ float w1t[2 * 992];   // [ci][c*31+k]
    const int tid = threadIdx.x;
    const int b = blockIdx.y;
    const int t0 = blockIdx.x * 256;

    for (int idx = tid; idx < 640; idx += 256) {
        int ci = idx / 320, xl = idx - ci * 320;
        int id = t0 - 15 + xl;
        float val = 0.f;
        if (xl < 286 && id >= 0 && id < TT) val = x[b * TT + id];
        xin[idx] = ci ? val * val : val;   // predictor input = cat([x, x*x])
    }
    for (int idx = tid; idx < 1984; idx += 256) {
        int c = idx / 62; int r = idx - c * 62; int ci = r / 31; int k = r - ci * 31;
        w1t[ci * 992 + c * 31 + k] = p1w[idx];
    }
    __syncthreads();

    const int tg = tid >> 5, c = tid & 31;
    float acc[32];
    const float bias = p1b[c];
#pragma unroll
    for (int i = 0; i < 32; ++i) acc[i] = bias;

    for (int h = 0; h < 4; ++h) {
        for (int ci = 0; ci < 2; ++ci) {
            float win[40];
            const float4* wp = (const float4*)(&xin[ci * 320 + tg * 32 + h * 8]);
#pragma unroll
            for (int r = 0; r < 10; ++r) {
                float4 q = wp[r];
                win[4*r] = q.x; win[4*r+1] = q.y; win[4*r+2] = q.z; win[4*r+3] = q.w;
            }
#pragma unroll
            for (int k = 0; k < 31; ++k) {
                float w = w1t[ci * 992 + c * 31 + k];
#pragma unroll
                for (int i = 0; i < 8; ++i) acc[h*8+i] = fmaf(w, win[i + k], acc[h*8+i]);
            }
        }
    }
    const float s = g1[c] * rsqrtf(v1[c] + 1e-5f);
    const float sh = b1[c] - m1[c] * s;
    float* up = &u[((size_t)(b * 32 + c)) * TT + t0 + tg * 32];
#pragma unroll
    for (int i = 0; i < 8; ++i) {
        float z0 = fmaf(acc[4*i+0], s, sh);
        float z1 = fmaf(acc[4*i+1], s, sh);
        float z2 = fmaf(acc[4*i+2], s, sh);
        float z3 = fmaf(acc[4*i+3], s, sh);
        ((float4*)up)[i] = make_float4(z0 * sig_(z0), z1 * sig_(z1), z2 * sig_(z2), z3 * sig_(z3));
    }
}

// ---------------- Kernel 1b: conv2 (32->32, k=15, pad7) + BN(1e-5) + swish -> v ----------------
__global__ __launch_bounds__(256) void k_conv2(
    const float* __restrict__ u,
    const float* __restrict__ p2w, const float* __restrict__ p2b,
    const float* __restrict__ g2, const float* __restrict__ b2,
    const float* __restrict__ m2, const float* __restrict__ v2,
    float* __restrict__ vout)
{
    __shared__ float uld[32 * 144];   // [ci][tl], tl -> t0-7+tl, valid tl<142
    __shared__ float w2t[32 * 240];   // [ci][cl*15+k]
    const int tid = threadIdx.x;
    const int b = blockIdx.y;
    const int t0 = blockIdx.x * 128;
    const int ch = blockIdx.z;        // c-half: c = ch*16 + cl

    for (int idx = tid; idx < 32 * 144; idx += 256) {
        int ci = idx / 144, tl = idx - ci * 144;
        int tg = t0 - 7 + tl;
        float val = 0.f;
        if (tl < 142 && tg >= 0 && tg < TT) val = u[((size_t)(b * 32 + ci)) * TT + tg];
        uld[idx] = val;
    }
    for (int idx = tid; idx < 32 * 240; idx += 256) {
        int ci = idx / 240; int r = idx - ci * 240; int cl = r / 15; int k = r - cl * 15;
        w2t[idx] = p2w[(ch * 16 + cl) * 480 + ci * 15 + k];
    }
    __syncthreads();

    const int tg = tid >> 4, cl = tid & 15;
    const int c = ch * 16 + cl;
    float acc[8];
    const float bias = p2b[c];
#pragma unroll
    for (int i = 0; i < 8; ++i) acc[i] = bias;

    for (int ci = 0; ci < 32; ++ci) {
        float win[24];
        const float4* wp = (const float4*)(&uld[ci * 144 + tg * 8]);
#pragma unroll
        for (int r = 0; r < 6; ++r) {
            float4 q = wp[r];
            win[4*r] = q.x; win[4*r+1] = q.y; win[4*r+2] = q.z; win[4*r+3] = q.w;
        }
#pragma unroll
        for (int k = 0; k < 15; ++k) {
            float w = w2t[ci * 240 + cl * 15 + k];
#pragma unroll
            for (int i = 0; i < 8; ++i) acc[i] = fmaf(w, win[i + k], acc[i]);
        }
    }
    const float s = g2[c] * rsqrtf(v2[c] + 1e-5f);
    const float sh = b2[c] - m2[c] * s;
    float o[8];
#pragma unroll
    for (int i = 0; i < 8; ++i) { float z = fmaf(acc[i], s, sh); o[i] = z * sig_(z); }
    float* vp = &vout[((size_t)(b * 32 + c)) * TT + t0 + tg * 8];
    ((float4*)vp)[0] = make_float4(o[0], o[1], o[2], o[3]);
    ((float4*)vp)[1] = make_float4(o[4], o[5], o[6], o[7]);
}

// ---------------- Kernel 1c: conv3 (32->2, k=15, pad7) + sigmoids ----------------
__global__ __launch_bounds__(256) void k_conv3(
    const float* __restrict__ vin,
    const float* __restrict__ p3w, const float* __restrict__ p3b,
    const float* __restrict__ nm,
    float* __restrict__ outw, float* __restrict__ outbm, float* __restrict__ moves)
{
    __shared__ float vld[32 * 272];   // [ci][tl], tl -> t0-7+tl, valid tl<270
    const int tid = threadIdx.x;
    const int b = blockIdx.y;
    const int t0 = blockIdx.x * 256;

    for (int idx = tid; idx < 32 * 272; idx += 256) {
        int ci = idx / 272, tl = idx - ci * 272;
        int tg = t0 - 7 + tl;
        float val = 0.f;
        if (tl < 270 && tg >= 0 && tg < TT) val = vin[((size_t)(b * 32 + ci)) * TT + tg];
        vld[idx] = val;
    }
    __syncthreads();

    float a0 = p3b[0], a1 = p3b[1];
    for (int ci = 0; ci < 32; ++ci) {
        float win[15];
#pragma unroll
        for (int k = 0; k < 15; ++k) win[k] = vld[ci * 272 + tid + k];
#pragma unroll
        for (int k = 0; k < 15; ++k) {
            a0 = fmaf(p3w[ci * 15 + k], win[k], a0);         // o=0
            a1 = fmaf(p3w[480 + ci * 15 + k], win[k], a1);   // o=1
        }
    }
    const int t = t0 + tid;
    const float wt = sig_(a0);
    const float bm = sig_(a1);
    outw[b * TT + t] = wt;
    outbm[b * TT + t] = bm;
    moves[b * TT + t] = bm * nm[0];
}

// ---------------- Kernel 2: scan + coefs + lens + segment bounds ----------------
// 1024 threads/batch, float4/thread, 2 serial chunks. Writes, for every integer
// lf in [-1, LFULL]: bnd[b][lf+1] = lower_bound(poses >= lf)  (TT if none).
__global__ __launch_bounds__(1024) void k_scan(
    const float* __restrict__ moves, const float* __restrict__ wts,
    float* __restrict__ coef1, float* __restrict__ coef2,
    int* __restrict__ bnd, float* __restrict__ lens)
{
    __shared__ float wsum[16];
    const int tid = threadIdx.x;
    const int b = blockIdx.x;
    const int lane = tid & 63, wv = tid >> 6;
    float carry = 0.f;

    int* bb = &bnd[b * BSTRIDE];
    for (int i = tid; i < BSTRIDE; i += 1024) bb[i] = TT;   // default: no t reaches lf
    if (tid == 0) { bb[0] = 0; bb[1] = 0; }                 // lf <= 0 -> t = 0 (poses[0] > 0)
    __syncthreads();   // init must not race with crossing writes below

    const float4* mv4 = (const float4*)&moves[b * TT];
    const float4* wt4 = (const float4*)&wts[b * TT];
    float4* c14 = (float4*)&coef1[b * TT];
    float4* c24 = (float4*)&coef2[b * TT];

    for (int chunk = 0; chunk < 2; ++chunk) {
        const int idx = chunk * 1024 + tid;
        float4 m = mv4[idx];
        const float s = m.x + m.y + m.z + m.w;
        float v = s;
#pragma unroll
        for (int off = 1; off < 64; off <<= 1) {
            float n = __shfl_up(v, off, 64);
            if (lane >= off) v += n;
        }
        if (lane == 63) wsum[wv] = v;
        __syncthreads();
        float pre = carry;
        for (int w = 0; w < wv; ++w) pre += wsum[w];
        float tot = 0.f;
#pragma unroll
        for (int w = 0; w < 16; ++w) tot += wsum[w];
        const float base = pre + (v - s);       // exclusive prefix before this thread's 4
        const float p0 = base + m.x;
        const float p1 = p0 + m.y;
        const float p2 = p1 + m.z;
        const float p3 = p2 + m.w;
        const float4 w4 = wt4[idx];
        const float fr0 = p0 - floorf(p0), fr1 = p1 - floorf(p1);
        const float fr2 = p2 - floorf(p2), fr3 = p3 - floorf(p3);
        c14[idx] = make_float4((1.f - fr0) * w4.x, (1.f - fr1) * w4.y,
                               (1.f - fr2) * w4.z, (1.f - fr3) * w4.w);
        c24[idx] = make_float4(fr0 * w4.x, fr1 * w4.y, fr2 * w4.z, fr3 * w4.w);
        // integer crossings in (base, p3]: lower_bound index for each
        {
            int lf = (int)floorf(base) + 1;
            const int lfe = (int)floorf(p3);
            const int tbase = idx << 2;
            for (; lf <= lfe; ++lf) {
                const float lff = (float)lf;
                int t = tbase;
                if (p0 >= lff) { }
                else if (p1 >= lff) t += 1;
                else if (p2 >= lff) t += 2;
                else t += 3;
                if (lf + 1 < BSTRIDE) bb[lf + 1] = t;
            }
        }
        if (chunk == 1 && tid == 1023) lens[b] = floorf(p3) + 2.0f;
        carry += tot;
        __syncthreads();
    }
}

// ---------------- Kernel 3: fused GLU-features + CIF pooling ----------------
static constexpr int LTILE = 16;
static constexpr int CHK = 128;

__global__ __launch_bounds__(256) void k_pool(
    const float* __restrict__ x,
    const float* __restrict__ cw,
    const float* __restrict__ bng, const float* __restrict__ bnb,
    const float* __restrict__ bnm, const float* __restrict__ bnv,
    const float* __restrict__ coef1, const float* __restrict__ coef2,
    const int* __restrict__ bnd,
    float* __restrict__ xevs)
{
    __shared__ float out_lds[256 * 17];     // [c][li], stride 17 (conflict-free)
    __shared__ float4 xl4[36];              // x window, chunk-staged (CHK+12 floats)
    __shared__ float4 c1l4[CHK / 4], c2l4[CHK / 4];
    __shared__ int lbs[LTILE + 2];
    float* xl = (float*)xl4;
    float* c1l = (float*)c1l4;
    float* c2l = (float*)c2l4;

    const int tid = threadIdx.x;
    const int b = blockIdx.y;
    const int l0 = blockIdx.x * LTILE;
    const int LTa = min(LTILE, LFULL - l0);

    if (tid < LTa + 2) lbs[tid] = bnd[b * BSTRIDE + l0 + tid];  // lf = l0-1+tid
    __syncthreads();

    const int t_lo = lbs[0];
    const int t_hi = lbs[LTa + 1];
    const size_t rowbase = (size_t)b * 256 * LFULL + l0;

    if (t_lo >= t_hi) {   // inactive tile: stream zeros straight to HBM
        const float4 z = make_float4(0.f, 0.f, 0.f, 0.f);
#pragma unroll
        for (int it = 0; it < 4; ++it) {
            int idx4 = it * 256 + tid;
            int cc = idx4 >> 2, q = (idx4 & 3) << 2;
            if (q < LTa)
                *(float4*)(&xevs[rowbase + (size_t)cc * LFULL + q]) = z;
        }
        return;
    }

    // zero own row (columns never emitted must read 0)
    {
#pragma unroll
        for (int li = 0; li < 17; ++li) out_lds[tid * 17 + li] = 0.f;
    }

    const int c = tid;
    float wa[9], wg[9];
#pragma unroll
    for (int k = 0; k < 9; ++k) { wa[k] = cw[c * 9 + k]; wg[k] = cw[(c + 256) * 9 + k]; }
    const float sa = bng[c] * rsqrtf(bnv[c] + 1e-3f);
    const float sha = bnb[c] - bnm[c] * sa;
    const float sg = bng[c + 256] * rsqrtf(bnv[c + 256] + 1e-3f);
    const float shg = bnb[c + 256] - bnm[c + 256] * sg;

    const float* xg = &x[b * TT];
    const float* c1g = &coef1[b * TT];
    const float* c2g = &coef2[b * TT];

    float accA = 0.f, accB = 0.f;   // accA: column j-1, accB: column j
    int j = 0;
    int nb = lbs[1];

    for (int cs = t_lo; cs < t_hi; cs += CHK) {
        const int ce = min(cs + CHK, t_hi);
        const int len = ce - cs;
        __syncthreads();           // previous chunk fully consumed
        for (int idx = tid; idx < len + 12; idx += 256) {
            int id = cs - 4 + idx;
            xl[idx] = (id >= 0 && id < TT) ? xg[id] : 0.f;
        }
        if (tid < len) { c1l[tid] = c1g[cs + tid]; c2l[tid] = c2g[cs + tid]; }
        __syncthreads();

        const int len4 = len >> 2;
        for (int g = 0; g < len4; ++g) {
            float4 A = xl4[g], Bq = xl4[g + 1], Cq = xl4[g + 2];
            float w[12] = {A.x, A.y, A.z, A.w, Bq.x, Bq.y, Bq.z, Bq.w, Cq.x, Cq.y, Cq.z, Cq.w};
            float f[4];
#pragma unroll
            for (int i = 0; i < 4; ++i) {
                float s0 = 0.f, s1 = 0.f;
#pragma unroll
                for (int k = 0; k < 9; ++k) { s0 = fmaf(wa[k], w[i + k], s0); s1 = fmaf(wg[k], w[i + k], s1); }
                const float av = fmaf(s0, sa, sha);
                const float gv = fmaf(s1, sg, shg);
                f[i] = av * sig_(gv);
            }
            float4 c1v = c1l4[g], c2v = c2l4[g];
            const float c1a[4] = {c1v.x, c1v.y, c1v.z, c1v.w};
            const float c2a[4] = {c2v.x, c2v.y, c2v.z, c2v.w};
            const int tb = cs + (g << 2);
#pragma unroll
            for (int i = 0; i < 4; ++i) {
                const int t = tb + i;
                while (t >= nb) {   // segment crossing(s)
                    int li = j - 1;
                    if (li >= 0 && li < LTa) out_lds[c * 17 + li] = accA;
                    accA = accB; accB = 0.f;
                    ++j;
                    nb = lbs[j + 1];
                }
                accA = fmaf(c1a[i], f[i], accA);
                accB = fmaf(c2a[i], f[i], accB);
            }
        }
        // tail (len not multiple of 4)
        for (int t = cs + (len4 << 2); t < ce; ++t) {
            const int il = t - cs;
            float s0 = 0.f, s1 = 0.f;
#pragma unroll
            for (int k = 0; k < 9; ++k) { float xv = xl[il + k]; s0 = fmaf(wa[k], xv, s0); s1 = fmaf(wg[k], xv, s1); }
            const float av = fmaf(s0, sa, sha);
            const float gv = fmaf(s1, sg, shg);
            const float f0 = av * sig_(gv);
            while (t >= nb) {
                int li = j - 1;
                if (li >= 0 && li < LTa) out_lds[c * 17 + li] = accA;
                accA = accB; accB = 0.f;
                ++j;
                nb = lbs[j + 1];
            }
            accA = fmaf(c1l[il], f0, accA);
            accB = fmaf(c2l[il], f0, accB);
        }
    }
    {   // trailing emit
        int li = j - 1;
        if (li >= 0 && li < LTa) out_lds[c * 17 + li] = accA;
    }
    __syncthreads();

#pragma unroll
    for (int it = 0; it < 4; ++it) {
        int idx4 = it * 256 + tid;
        int cc = idx4 >> 2, q = (idx4 & 3) << 2;
        if (q < LTa) {
            float4 o;
            o.x = out_lds[cc * 17 + q + 0];
            o.y = out_lds[cc * 17 + q + 1];
            o.z = out_lds[cc * 17 + q + 2];
            o.w = out_lds[cc * 17 + q + 3];
            *(float4*)(&xevs[rowbase + (size_t)cc * LFULL + q]) = o;
        }
    }
}

extern "C" void kernel_launch(void* const* d_in, const int* in_sizes, int n_in,
                              void* d_out, int out_size, void* d_ws, size_t ws_size,
                              hipStream_t stream) {
    (void)in_sizes; (void)n_in; (void)out_size; (void)ws_size;
    const float* x      = (const float*)d_in[0];
    const float* conv_w = (const float*)d_in[1];
    const float* bn_g   = (const float*)d_in[2];
    const float* bn_b   = (const float*)d_in[3];
    const float* bn_m   = (const float*)d_in[4];
    const float* bn_v   = (const float*)d_in[5];
    const float* p1_w   = (const float*)d_in[6];
    const float* p1_b   = (const float*)d_in[7];
    const float* pbn1_g = (const float*)d_in[8];
    const float* pbn1_b = (const float*)d_in[9];
    const float* pbn1_m = (const float*)d_in[10];
    const float* pbn1_v = (const float*)d_in[11];
    const float* p2_w   = (const float*)d_in[12];
    const float* p2_b   = (const float*)d_in[13];
    const float* pbn2_g = (const float*)d_in[14];
    const float* pbn2_b = (const float*)d_in[15];
    const float* pbn2_m = (const float*)d_in[16];
    const float* pbn2_v = (const float*)d_in[17];
    const float* p3_w   = (const float*)d_in[18];
    const float* p3_b   = (const float*)d_in[19];
    const float* nm     = (const float*)d_in[20];

    float* out = (float*)d_out;
    float* ws  = (float*)d_ws;
    float* u     = ws + U_OFF;
    float* v     = ws + V_OFF;
    float* moves = ws + MOVES_OFF;
    float* coef1 = ws + C1_OFF;
    float* coef2 = ws + C2_OFF;
    int*   bnd   = (int*)(ws + BND_OFF);   // overlays u — u is dead after k_conv2
    float* xevs  = out + XE_OFF;
    float* lens  = out + LENS_OFF;
    float* bmv   = out + BM_OFF;
    float* wts   = out + WT_OFF;

    k_conv1<<<dim3(32, 16), 256, 0, stream>>>(x, p1_w, p1_b, pbn1_g, pbn1_b, pbn1_m, pbn1_v, u);
    k_conv2<<<dim3(64, 16, 2), 256, 0, stream>>>(u, p2_w, p2_b, pbn2_g, pbn2_b, pbn2_m, pbn2_v, v);
    k_conv3<<<dim3(32, 16), 256, 0, stream>>>(v, p3_w, p3_b, nm, wts, bmv, moves);
    k_scan<<<16, 1024, 0, stream>>>(moves, wts, coef1, coef2, bnd, lens);
    k_pool<<<dim3((LFULL + LTILE - 1) / LTILE, 16), 256, 0, stream>>>(
        x, conv_w, bn_g, bn_b, bn_m, bn_v, coef1, coef2, bnd, xevs);
}

// Round 4
// 358.332 us; speedup vs baseline: 1.0515x; 1.0515x over previous
//
#include <hip/hip_runtime.h>
#include <math.h>

// Problem constants
static constexpr int TT = 8192;          // sequence length
static constexpr int LFULL = 8196;       // Lmax (8194) + pad to mult of 3 (2)
static constexpr int BSTRIDE = LFULL + 2; // bounds per-batch stride (lf+1 for lf in [-1, LFULL])

// d_out layout (floats, concatenated in reference return order)
static constexpr size_t XE_OFF   = 0;                       // [16][256][8196]
static constexpr size_t LENS_OFF = (size_t)16*256*LFULL;
static constexpr size_t BM_OFF   = LENS_OFF + 16;           // bmoves [16][8192]
static constexpr size_t WT_OFF   = BM_OFF + (size_t)16*TT;  // weights [16][8192]

// ws layout (floats). bnd overlays u (u is dead after k_conv2; same-stream ordering).
static constexpr size_t U_OFF     = 0;                        // [16][32][8192]
static constexpr size_t V_OFF     = U_OFF + (size_t)16*32*TT; // [16][32][8192]
static constexpr size_t MOVES_OFF = V_OFF + (size_t)16*32*TT;
static constexpr size_t C1_OFF    = MOVES_OFF + (size_t)16*TT;
static constexpr size_t C2_OFF    = C1_OFF + (size_t)16*TT;
static constexpr size_t BND_OFF   = U_OFF;                    // int[16][BSTRIDE], 525 KB << 16.8 MB

__device__ __forceinline__ float sig_(float z) { return 1.0f / (1.0f + __expf(-z)); }

// ---------------- Kernel 1a: conv1 (2->32, k=31, pad15) + BN(1e-5) + swish -> u ----------------
__global__ __launch_bounds__(256) void k_conv1(
    const float* __restrict__ x,
    const float* __restrict__ p1w, const float* __restrict__ p1b,
    const float* __restrict__ g1, const float* __restrict__ b1,
    const float* __restrict__ m1, const float* __restrict__ v1,
    float* __restrict__ u)
{
    __shared__ float xin[2 * 320];   // [ci][xl], xl -> t0-15+xl, valid xl<286
    __shared__ float w1t[2 * 992];   // [ci][c*31+k]
    const int tid = threadIdx.x;
    const int b = blockIdx.y;
    const int t0 = blockIdx.x * 256;

    for (int idx = tid; idx < 640; idx += 256) {
        int ci = idx / 320, xl = idx - ci * 320;
        int id = t0 - 15 + xl;
        float val = 0.f;
        if (xl < 286 && id >= 0 && id < TT) val = x[b * TT + id];
        xin[idx] = ci ? val * val : val;   // predictor input = cat([x, x*x])
    }
    for (int idx = tid; idx < 1984; idx += 256) {
        int c = idx / 62; int r = idx - c * 62; int ci = r / 31; int k = r - ci * 31;
        w1t[ci * 992 + c * 31 + k] = p1w[idx];
    }
    __syncthreads();

    const int tg = tid >> 5, c = tid & 31;
    float acc[32];
    const float bias = p1b[c];
#pragma unroll
    for (int i = 0; i < 32; ++i) acc[i] = bias;

    for (int h = 0; h < 4; ++h) {
        for (int ci = 0; ci < 2; ++ci) {
            float win[40];
            const float4* wp = (const float4*)(&xin[ci * 320 + tg * 32 + h * 8]);
#pragma unroll
            for (int r = 0; r < 10; ++r) {
                float4 q = wp[r];
                win[4*r] = q.x; win[4*r+1] = q.y; win[4*r+2] = q.z; win[4*r+3] = q.w;
            }
#pragma unroll
            for (int k = 0; k < 31; ++k) {
                float w = w1t[ci * 992 + c * 31 + k];
#pragma unroll
                for (int i = 0; i < 8; ++i) acc[h*8+i] = fmaf(w, win[i + k], acc[h*8+i]);
            }
        }
    }
    const float s = g1[c] * rsqrtf(v1[c] + 1e-5f);
    const float sh = b1[c] - m1[c] * s;
    float* up = &u[((size_t)(b * 32 + c)) * TT + t0 + tg * 32];
#pragma unroll
    for (int i = 0; i < 8; ++i) {
        float z0 = fmaf(acc[4*i+0], s, sh);
        float z1 = fmaf(acc[4*i+1], s, sh);
        float z2 = fmaf(acc[4*i+2], s, sh);
        float z3 = fmaf(acc[4*i+3], s, sh);
        ((float4*)up)[i] = make_float4(z0 * sig_(z0), z1 * sig_(z1), z2 * sig_(z2), z3 * sig_(z3));
    }
}

// ---------------- Kernel 1b: conv2 (32->32, k=15, pad7) + BN(1e-5) + swish -> v ----------------
// ci-dim split into two staged halves: LDS 24.6 KB -> ~6 blocks/CU (was 61 KB -> 2).
__global__ __launch_bounds__(256) void k_conv2(
    const float* __restrict__ u,
    const float* __restrict__ p2w, const float* __restrict__ p2b,
    const float* __restrict__ g2, const float* __restrict__ b2,
    const float* __restrict__ m2, const float* __restrict__ v2,
    float* __restrict__ vout)
{
    __shared__ float uld[16 * 144];   // [ci][tl], tl -> t0-7+tl, valid tl<142
    __shared__ float w2t[16 * 240];   // [ci][cl*15+k]
    const int tid = threadIdx.x;
    const int b = blockIdx.y;
    const int t0 = blockIdx.x * 128;
    const int ch = blockIdx.z;        // c-half: c = ch*16 + cl

    const int tg = tid >> 4, cl = tid & 15;
    const int c = ch * 16 + cl;
    float acc[8];
    const float bias = p2b[c];
#pragma unroll
    for (int i = 0; i < 8; ++i) acc[i] = bias;

    for (int h = 0; h < 2; ++h) {
        __syncthreads();   // previous half fully consumed
        for (int idx = tid; idx < 16 * 144; idx += 256) {
            int ci = idx / 144, tl = idx - ci * 144;
            int tgl = t0 - 7 + tl;
            float val = 0.f;
            if (tl < 142 && tgl >= 0 && tgl < TT) val = u[((size_t)(b * 32 + h * 16 + ci)) * TT + tgl];
            uld[idx] = val;
        }
        for (int idx = tid; idx < 16 * 240; idx += 256) {
            int ci = idx / 240; int r = idx - ci * 240; int cl2 = r / 15; int k = r - cl2 * 15;
            w2t[idx] = p2w[(ch * 16 + cl2) * 480 + (h * 16 + ci) * 15 + k];
        }
        __syncthreads();

        for (int ci = 0; ci < 16; ++ci) {
            float win[24];
            const float4* wp = (const float4*)(&uld[ci * 144 + tg * 8]);
#pragma unroll
            for (int r = 0; r < 6; ++r) {
                float4 q = wp[r];
                win[4*r] = q.x; win[4*r+1] = q.y; win[4*r+2] = q.z; win[4*r+3] = q.w;
            }
#pragma unroll
            for (int k = 0; k < 15; ++k) {
                float w = w2t[ci * 240 + cl * 15 + k];
#pragma unroll
                for (int i = 0; i < 8; ++i) acc[i] = fmaf(w, win[i + k], acc[i]);
            }
        }
    }
    const float s = g2[c] * rsqrtf(v2[c] + 1e-5f);
    const float sh = b2[c] - m2[c] * s;
    float o[8];
#pragma unroll
    for (int i = 0; i < 8; ++i) { float z = fmaf(acc[i], s, sh); o[i] = z * sig_(z); }
    float* vp = &vout[((size_t)(b * 32 + c)) * TT + t0 + tg * 8];
    ((float4*)vp)[0] = make_float4(o[0], o[1], o[2], o[3]);
    ((float4*)vp)[1] = make_float4(o[4], o[5], o[6], o[7]);
}

// ---------------- Kernel 1c: conv3 (32->2, k=15, pad7) + sigmoids ----------------
__global__ __launch_bounds__(256) void k_conv3(
    const float* __restrict__ vin,
    const float* __restrict__ p3w, const float* __restrict__ p3b,
    const float* __restrict__ nm,
    float* __restrict__ outw, float* __restrict__ outbm, float* __restrict__ moves)
{
    __shared__ float vld[32 * 272];   // [ci][tl], tl -> t0-7+tl, valid tl<270
    const int tid = threadIdx.x;
    const int b = blockIdx.y;
    const int t0 = blockIdx.x * 256;

    for (int idx = tid; idx < 32 * 272; idx += 256) {
        int ci = idx / 272, tl = idx - ci * 272;
        int tg = t0 - 7 + tl;
        float val = 0.f;
        if (tl < 270 && tg >= 0 && tg < TT) val = vin[((size_t)(b * 32 + ci)) * TT + tg];
        vld[idx] = val;
    }
    __syncthreads();

    float a0 = p3b[0], a1 = p3b[1];
    for (int ci = 0; ci < 32; ++ci) {
        float win[15];
#pragma unroll
        for (int k = 0; k < 15; ++k) win[k] = vld[ci * 272 + tid + k];
#pragma unroll
        for (int k = 0; k < 15; ++k) {
            a0 = fmaf(p3w[ci * 15 + k], win[k], a0);         // o=0
            a1 = fmaf(p3w[480 + ci * 15 + k], win[k], a1);   // o=1
        }
    }
    const int t = t0 + tid;
    const float wt = sig_(a0);
    const float bm = sig_(a1);
    outw[b * TT + t] = wt;
    outbm[b * TT + t] = bm;
    moves[b * TT + t] = bm * nm[0];
}

// ---------------- Kernel 2: scan + coefs + lens + segment bounds ----------------
// 1024 threads/batch, float4/thread, 2 serial chunks. Writes, for every integer
// lf in [-1, LFULL]: bnd[b][lf+1] = lower_bound(poses >= lf)  (TT if none).
__global__ __launch_bounds__(1024) void k_scan(
    const float* __restrict__ moves, const float* __restrict__ wts,
    float* __restrict__ coef1, float* __restrict__ coef2,
    int* __restrict__ bnd, float* __restrict__ lens)
{
    __shared__ float wsum[16];
    const int tid = threadIdx.x;
    const int b = blockIdx.x;
    const int lane = tid & 63, wv = tid >> 6;
    float carry = 0.f;

    int* bb = &bnd[b * BSTRIDE];
    for (int i = tid; i < BSTRIDE; i += 1024) bb[i] = TT;   // default: no t reaches lf
    if (tid == 0) { bb[0] = 0; bb[1] = 0; }                 // lf <= 0 -> t = 0 (poses[0] > 0)
    __syncthreads();   // init must not race with crossing writes below

    const float4* mv4 = (const float4*)&moves[b * TT];
    const float4* wt4 = (const float4*)&wts[b * TT];
    float4* c14 = (float4*)&coef1[b * TT];
    float4* c24 = (float4*)&coef2[b * TT];

    for (int chunk = 0; chunk < 2; ++chunk) {
        const int idx = chunk * 1024 + tid;
        float4 m = mv4[idx];
        const float s = m.x + m.y + m.z + m.w;
        float v = s;
#pragma unroll
        for (int off = 1; off < 64; off <<= 1) {
            float n = __shfl_up(v, off, 64);
            if (lane >= off) v += n;
        }
        if (lane == 63) wsum[wv] = v;
        __syncthreads();
        float pre = carry;
        for (int w = 0; w < wv; ++w) pre += wsum[w];
        float tot = 0.f;
#pragma unroll
        for (int w = 0; w < 16; ++w) tot += wsum[w];
        const float base = pre + (v - s);       // exclusive prefix before this thread's 4
        const float p0 = base + m.x;
        const float p1 = p0 + m.y;
        const float p2 = p1 + m.z;
        const float p3 = p2 + m.w;
        const float4 w4 = wt4[idx];
        const float fr0 = p0 - floorf(p0), fr1 = p1 - floorf(p1);
        const float fr2 = p2 - floorf(p2), fr3 = p3 - floorf(p3);
        c14[idx] = make_float4((1.f - fr0) * w4.x, (1.f - fr1) * w4.y,
                               (1.f - fr2) * w4.z, (1.f - fr3) * w4.w);
        c24[idx] = make_float4(fr0 * w4.x, fr1 * w4.y, fr2 * w4.z, fr3 * w4.w);
        // integer crossings in (base, p3]: lower_bound index for each
        {
            int lf = (int)floorf(base) + 1;
            const int lfe = (int)floorf(p3);
            const int tbase = idx << 2;
            for (; lf <= lfe; ++lf) {
                const float lff = (float)lf;
                int t = tbase;
                if (p0 >= lff) { }
                else if (p1 >= lff) t += 1;
                else if (p2 >= lff) t += 2;
                else t += 3;
                if (lf + 1 < BSTRIDE) bb[lf + 1] = t;
            }
        }
        if (chunk == 1 && tid == 1023) lens[b] = floorf(p3) + 2.0f;
        carry += tot;
        __syncthreads();
    }
}

// ---------------- Kernel 2b: stream zeros over the inactive column range ----------------
// Inactive tiles satisfy l0 >= lens[b]; k_pool writes all columns of active tiles
// (zero-padding its own tail), so zeroing rows from ceil16(lens[b]) partitions exactly.
__global__ __launch_bounds__(256) void k_zero(
    const float* __restrict__ lens, float* __restrict__ xevs)
{
    const int b = blockIdx.y;
    const int cg = blockIdx.x;        // 16 channel rows per block
    const int zs = (((int)lens[b]) + 15) & ~15;
    if (zs >= LFULL) return;
    const int n4 = (LFULL - zs) >> 2; // zs, LFULL both multiples of 4
    const float4 z = make_float4(0.f, 0.f, 0.f, 0.f);
    for (int r = 0; r < 16; ++r) {
        float4* row4 = (float4*)&xevs[((size_t)(b * 256 + cg * 16 + r)) * LFULL + zs];
        for (int i = threadIdx.x; i < n4; i += 256) row4[i] = z;
    }
}

// ---------------- Kernel 3: fused GLU-features + CIF pooling (active tiles only) ----------------
static constexpr int LTILE = 16;
static constexpr int CHK = 128;

__global__ __launch_bounds__(256) void k_pool(
    const float* __restrict__ x,
    const float* __restrict__ cw,
    const float* __restrict__ bng, const float* __restrict__ bnb,
    const float* __restrict__ bnm, const float* __restrict__ bnv,
    const float* __restrict__ coef1, const float* __restrict__ coef2,
    const int* __restrict__ bnd,
    float* __restrict__ xevs)
{
    __shared__ float out_lds[256 * 17];     // [c][li], stride 17 (conflict-free)
    __shared__ float4 xl4[36];              // x window, chunk-staged (CHK+12 floats)
    __shared__ float4 c1l4[CHK / 4], c2l4[CHK / 4];
    __shared__ int lbs[LTILE + 2];
    float* xl = (float*)xl4;
    float* c1l = (float*)c1l4;
    float* c2l = (float*)c2l4;

    const int tid = threadIdx.x;
    const int b = blockIdx.y;
    const int l0 = blockIdx.x * LTILE;
    const int LTa = min(LTILE, LFULL - l0);

    if (tid < LTa + 2) lbs[tid] = bnd[b * BSTRIDE + l0 + tid];  // lf = l0-1+tid
    __syncthreads();

    const int t_lo = lbs[0];
    const int t_hi = lbs[LTa + 1];
    if (t_lo >= t_hi) return;   // inactive tile: k_zero covers it

    const size_t rowbase = (size_t)b * 256 * LFULL + l0;

    // zero own row (columns never emitted must read 0)
#pragma unroll
    for (int li = 0; li < 17; ++li) out_lds[tid * 17 + li] = 0.f;

    const int c = tid;
    float wa[9], wg[9];
#pragma unroll
    for (int k = 0; k < 9; ++k) { wa[k] = cw[c * 9 + k]; wg[k] = cw[(c + 256) * 9 + k]; }
    const float sa = bng[c] * rsqrtf(bnv[c] + 1e-3f);
    const float sha = bnb[c] - bnm[c] * sa;
    const float sg = bng[c + 256] * rsqrtf(bnv[c + 256] + 1e-3f);
    const float shg = bnb[c + 256] - bnm[c + 256] * sg;

    const float* xg = &x[b * TT];
    const float* c1g = &coef1[b * TT];
    const float* c2g = &coef2[b * TT];

    float accA = 0.f, accB = 0.f;   // accA: column j-1, accB: column j
    int j = 0;
    int nb = lbs[1];

    for (int cs = t_lo; cs < t_hi; cs += CHK) {
        const int ce = min(cs + CHK, t_hi);
        const int len = ce - cs;
        __syncthreads();           // previous chunk fully consumed
        for (int idx = tid; idx < len + 12; idx += 256) {
            int id = cs - 4 + idx;
            xl[idx] = (id >= 0 && id < TT) ? xg[id] : 0.f;
        }
        if (tid < len) { c1l[tid] = c1g[cs + tid]; c2l[tid] = c2g[cs + tid]; }
        __syncthreads();

        const int len4 = len >> 2;
        for (int g = 0; g < len4; ++g) {
            float4 A = xl4[g], Bq = xl4[g + 1], Cq = xl4[g + 2];
            float w[12] = {A.x, A.y, A.z, A.w, Bq.x, Bq.y, Bq.z, Bq.w, Cq.x, Cq.y, Cq.z, Cq.w};
            float f[4];
#pragma unroll
            for (int i = 0; i < 4; ++i) {
                float s0 = 0.f, s1 = 0.f;
#pragma unroll
                for (int k = 0; k < 9; ++k) { s0 = fmaf(wa[k], w[i + k], s0); s1 = fmaf(wg[k], w[i + k], s1); }
                const float av = fmaf(s0, sa, sha);
                const float gv = fmaf(s1, sg, shg);
                f[i] = av * sig_(gv);
            }
            float4 c1v = c1l4[g], c2v = c2l4[g];
            const float c1a[4] = {c1v.x, c1v.y, c1v.z, c1v.w};
            const float c2a[4] = {c2v.x, c2v.y, c2v.z, c2v.w};
            const int tb = cs + (g << 2);
#pragma unroll
            for (int i = 0; i < 4; ++i) {
                const int t = tb + i;
                while (t >= nb) {   // segment crossing(s)
                    int li = j - 1;
                    if (li >= 0 && li < LTa) out_lds[c * 17 + li] = accA;
                    accA = accB; accB = 0.f;
                    ++j;
                    nb = lbs[j + 1];
                }
                accA = fmaf(c1a[i], f[i], accA);
                accB = fmaf(c2a[i], f[i], accB);
            }
        }
        // tail (len not multiple of 4)
        for (int t = cs + (len4 << 2); t < ce; ++t) {
            const int il = t - cs;
            float s0 = 0.f, s1 = 0.f;
#pragma unroll
            for (int k = 0; k < 9; ++k) { float xv = xl[il + k]; s0 = fmaf(wa[k], xv, s0); s1 = fmaf(wg[k], xv, s1); }
            const float av = fmaf(s0, sa, sha);
            const float gv = fmaf(s1, sg, shg);
            const float f0 = av * sig_(gv);
            while (t >= nb) {
                int li = j - 1;
                if (li >= 0 && li < LTa) out_lds[c * 17 + li] = accA;
                accA = accB; accB = 0.f;
                ++j;
                nb = lbs[j + 1];
            }
            accA = fmaf(c1l[il], f0, accA);
            accB = fmaf(c2l[il], f0, accB);
        }
    }
    {   // trailing emit
        int li = j - 1;
        if (li >= 0 && li < LTa) out_lds[c * 17 + li] = accA;
    }
    __syncthreads();

#pragma unroll
    for (int it = 0; it < 4; ++it) {
        int idx4 = it * 256 + tid;
        int cc = idx4 >> 2, q = (idx4 & 3) << 2;
        if (q < LTa) {
            float4 o;
            o.x = out_lds[cc * 17 + q + 0];
            o.y = out_lds[cc * 17 + q + 1];
            o.z = out_lds[cc * 17 + q + 2];
            o.w = out_lds[cc * 17 + q + 3];
            *(float4*)(&xevs[rowbase + (size_t)cc * LFULL + q]) = o;
        }
    }
}

extern "C" void kernel_launch(void* const* d_in, const int* in_sizes, int n_in,
                              void* d_out, int out_size, void* d_ws, size_t ws_size,
                              hipStream_t stream) {
    (void)in_sizes; (void)n_in; (void)out_size; (void)ws_size;
    const float* x      = (const float*)d_in[0];
    const float* conv_w = (const float*)d_in[1];
    const float* bn_g   = (const float*)d_in[2];
    const float* bn_b   = (const float*)d_in[3];
    const float* bn_m   = (const float*)d_in[4];
    const float* bn_v   = (const float*)d_in[5];
    const float* p1_w   = (const float*)d_in[6];
    const float* p1_b   = (const float*)d_in[7];
    const float* pbn1_g = (const float*)d_in[8];
    const float* pbn1_b = (const float*)d_in[9];
    const float* pbn1_m = (const float*)d_in[10];
    const float* pbn1_v = (const float*)d_in[11];
    const float* p2_w   = (const float*)d_in[12];
    const float* p2_b   = (const float*)d_in[13];
    const float* pbn2_g = (const float*)d_in[14];
    const float* pbn2_b = (const float*)d_in[15];
    const float* pbn2_m = (const float*)d_in[16];
    const float* pbn2_v = (const float*)d_in[17];
    const float* p3_w   = (const float*)d_in[18];
    const float* p3_b   = (const float*)d_in[19];
    const float* nm     = (const float*)d_in[20];

    float* out = (float*)d_out;
    float* ws  = (float*)d_ws;
    float* u     = ws + U_OFF;
    float* v     = ws + V_OFF;
    float* moves = ws + MOVES_OFF;
    float* coef1 = ws + C1_OFF;
    float* coef2 = ws + C2_OFF;
    int*   bnd   = (int*)(ws + BND_OFF);   // overlays u — u is dead after k_conv2
    float* xevs  = out + XE_OFF;
    float* lens  = out + LENS_OFF;
    float* bmv   = out + BM_OFF;
    float* wts   = out + WT_OFF;

    k_conv1<<<dim3(32, 16), 256, 0, stream>>>(x, p1_w, p1_b, pbn1_g, pbn1_b, pbn1_m, pbn1_v, u);
    k_conv2<<<dim3(64, 16, 2), 256, 0, stream>>>(u, p2_w, p2_b, pbn2_g, pbn2_b, pbn2_m, pbn2_v, v);
    k_conv3<<<dim3(32, 16), 256, 0, stream>>>(v, p3_w, p3_b, nm, wts, bmv, moves);
    k_scan<<<16, 1024, 0, stream>>>(moves, wts, coef1, coef2, bnd, lens);
    k_zero<<<dim3(16, 16), 256, 0, stream>>>(lens, xevs);
    k_pool<<<dim3((LFULL + LTILE - 1) / LTILE, 16), 256, 0, stream>>>(
        x, conv_w, bn_g, bn_b, bn_m, bn_v, coef1, coef2, bnd, xevs);
}

// Round 5
// 355.880 us; speedup vs baseline: 1.0587x; 1.0069x over previous
//
#include <hip/hip_runtime.h>
#include <math.h>

// Problem constants
static constexpr int TT = 8192;          // sequence length
static constexpr int LFULL = 8196;       // Lmax (8194) + pad to mult of 3 (2)
static constexpr int BSTRIDE = LFULL + 2; // bounds per-batch stride (lf+1 for lf in [-1, LFULL])

// d_out layout (floats, concatenated in reference return order)
static constexpr size_t XE_OFF   = 0;                       // [16][256][8196]
static constexpr size_t LENS_OFF = (size_t)16*256*LFULL;
static constexpr size_t BM_OFF   = LENS_OFF + 16;           // bmoves [16][8192]
static constexpr size_t WT_OFF   = BM_OFF + (size_t)16*TT;  // weights [16][8192]

// ws layout (floats). bnd overlays u (u is dead after k_conv2; same-stream ordering).
static constexpr size_t U_OFF     = 0;                        // [16][32][8192]
static constexpr size_t V_OFF     = U_OFF + (size_t)16*32*TT; // [16][32][8192]
static constexpr size_t MOVES_OFF = V_OFF + (size_t)16*32*TT;
static constexpr size_t C1_OFF    = MOVES_OFF + (size_t)16*TT;
static constexpr size_t C2_OFF    = C1_OFF + (size_t)16*TT;
static constexpr size_t BND_OFF   = U_OFF;                    // int[16][BSTRIDE], 525 KB << 16.8 MB

__device__ __forceinline__ float sig_(float z) { return 1.0f / (1.0f + __expf(-z)); }

// ---------------- Kernel 1a: conv1 (2->32, k=31, pad15) + BN(1e-5) + swish -> u ----------------
__global__ __launch_bounds__(256) void k_conv1(
    const float* __restrict__ x,
    const float* __restrict__ p1w, const float* __restrict__ p1b,
    const float* __restrict__ g1, const float* __restrict__ b1,
    const float* __restrict__ m1, const float* __restrict__ v1,
    float* __restrict__ u)
{
    __shared__ float xin[2 * 320];   // [ci][xl], xl -> t0-15+xl, valid xl<286
    __shared__ float w1t[2 * 992];   // [ci][c*31+k]
    const int tid = threadIdx.x;
    const int b = blockIdx.y;
    const int t0 = blockIdx.x * 256;

    for (int idx = tid; idx < 640; idx += 256) {
        int ci = idx / 320, xl = idx - ci * 320;
        int id = t0 - 15 + xl;
        float val = 0.f;
        if (xl < 286 && id >= 0 && id < TT) val = x[b * TT + id];
        xin[idx] = ci ? val * val : val;   // predictor input = cat([x, x*x])
    }
    for (int idx = tid; idx < 1984; idx += 256) {
        int c = idx / 62; int r = idx - c * 62; int ci = r / 31; int k = r - ci * 31;
        w1t[ci * 992 + c * 31 + k] = p1w[idx];
    }
    __syncthreads();

    const int tg = tid >> 5, c = tid & 31;
    float acc[32];
    const float bias = p1b[c];
#pragma unroll
    for (int i = 0; i < 32; ++i) acc[i] = bias;

    for (int h = 0; h < 4; ++h) {
        for (int ci = 0; ci < 2; ++ci) {
            float win[40];
            const float4* wp = (const float4*)(&xin[ci * 320 + tg * 32 + h * 8]);
#pragma unroll
            for (int r = 0; r < 10; ++r) {
                float4 q = wp[r];
                win[4*r] = q.x; win[4*r+1] = q.y; win[4*r+2] = q.z; win[4*r+3] = q.w;
            }
#pragma unroll
            for (int k = 0; k < 31; ++k) {
                float w = w1t[ci * 992 + c * 31 + k];
#pragma unroll
                for (int i = 0; i < 8; ++i) acc[h*8+i] = fmaf(w, win[i + k], acc[h*8+i]);
            }
        }
    }
    const float s = g1[c] * rsqrtf(v1[c] + 1e-5f);
    const float sh = b1[c] - m1[c] * s;
    float* up = &u[((size_t)(b * 32 + c)) * TT + t0 + tg * 32];
#pragma unroll
    for (int i = 0; i < 8; ++i) {
        float z0 = fmaf(acc[4*i+0], s, sh);
        float z1 = fmaf(acc[4*i+1], s, sh);
        float z2 = fmaf(acc[4*i+2], s, sh);
        float z3 = fmaf(acc[4*i+3], s, sh);
        ((float4*)up)[i] = make_float4(z0 * sig_(z0), z1 * sig_(z1), z2 * sig_(z2), z3 * sig_(z3));
    }
}

// ---------------- Kernel 1b: conv2 (32->32, k=15, pad7) + BN(1e-5) + swish -> v ----------------
// 16 t per thread, 256-t tiles, ci split in two staged halves, weights padded to 16 for b128.
__global__ __launch_bounds__(256) void k_conv2(
    const float* __restrict__ u,
    const float* __restrict__ p2w, const float* __restrict__ p2b,
    const float* __restrict__ g2, const float* __restrict__ b2,
    const float* __restrict__ m2, const float* __restrict__ v2,
    float* __restrict__ vout)
{
    __shared__ float uld[16 * 272];   // [ci][tl], tl -> t0-7+tl, valid tl<270
    __shared__ float w2t[16 * 256];   // [ci][cl*16+k], k=15 zero-padded
    const int tid = threadIdx.x;
    const int b = blockIdx.y;
    const int t0 = blockIdx.x * 256;
    const int ch = blockIdx.z;        // c-half: c = ch*16 + cl

    const int tg = tid >> 4, cl = tid & 15;
    const int c = ch * 16 + cl;
    float acc[16];
    const float bias = p2b[c];
#pragma unroll
    for (int i = 0; i < 16; ++i) acc[i] = bias;

    for (int h = 0; h < 2; ++h) {
        __syncthreads();   // previous half fully consumed
        for (int idx = tid; idx < 16 * 272; idx += 256) {
            int ci = idx >> 8; int tl = idx & 255;            // note: 272 != 256; do exact div
            ci = idx / 272; tl = idx - ci * 272;
            int tgl = t0 - 7 + tl;
            float val = 0.f;
            if (tl < 270 && tgl >= 0 && tgl < TT) val = u[((size_t)(b * 32 + h * 16 + ci)) * TT + tgl];
            uld[idx] = val;
        }
        for (int idx = tid; idx < 16 * 256; idx += 256) {
            int ci = idx >> 8; int r = idx & 255; int cl2 = r >> 4; int k = r & 15;
            w2t[idx] = (k < 15) ? p2w[(ch * 16 + cl2) * 480 + (h * 16 + ci) * 15 + k] : 0.f;
        }
        __syncthreads();

        for (int ci = 0; ci < 16; ++ci) {
            float win[32];
            const float4* wp = (const float4*)(&uld[ci * 272 + tg * 16]);
#pragma unroll
            for (int r = 0; r < 8; ++r) {
                float4 q = wp[r];
                win[4*r] = q.x; win[4*r+1] = q.y; win[4*r+2] = q.z; win[4*r+3] = q.w;
            }
            float w[16];
            const float4* wqp = (const float4*)(&w2t[ci * 256 + cl * 16]);
#pragma unroll
            for (int r = 0; r < 4; ++r) {
                float4 q = wqp[r];
                w[4*r] = q.x; w[4*r+1] = q.y; w[4*r+2] = q.z; w[4*r+3] = q.w;
            }
#pragma unroll
            for (int k = 0; k < 15; ++k) {
#pragma unroll
                for (int i = 0; i < 16; ++i) acc[i] = fmaf(w[k], win[i + k], acc[i]);
            }
        }
    }
    const float s = g2[c] * rsqrtf(v2[c] + 1e-5f);
    const float sh = b2[c] - m2[c] * s;
    float o[16];
#pragma unroll
    for (int i = 0; i < 16; ++i) { float z = fmaf(acc[i], s, sh); o[i] = z * sig_(z); }
    float* vp = &vout[((size_t)(b * 32 + c)) * TT + t0 + tg * 16];
#pragma unroll
    for (int r = 0; r < 4; ++r)
        ((float4*)vp)[r] = make_float4(o[4*r], o[4*r+1], o[4*r+2], o[4*r+3]);
}

// ---------------- Kernel 1c: conv3 (32->2, k=15, pad7) + sigmoids ----------------
__global__ __launch_bounds__(256) void k_conv3(
    const float* __restrict__ vin,
    const float* __restrict__ p3w, const float* __restrict__ p3b,
    const float* __restrict__ nm,
    float* __restrict__ outw, float* __restrict__ outbm, float* __restrict__ moves)
{
    __shared__ float vld[32 * 272];   // [ci][tl], tl -> t0-7+tl, valid tl<270
    const int tid = threadIdx.x;
    const int b = blockIdx.y;
    const int t0 = blockIdx.x * 256;

    for (int idx = tid; idx < 32 * 272; idx += 256) {
        int ci = idx / 272, tl = idx - ci * 272;
        int tg = t0 - 7 + tl;
        float val = 0.f;
        if (tl < 270 && tg >= 0 && tg < TT) val = vin[((size_t)(b * 32 + ci)) * TT + tg];
        vld[idx] = val;
    }
    __syncthreads();

    float a0 = p3b[0], a1 = p3b[1];
    for (int ci = 0; ci < 32; ++ci) {
        float win[15];
#pragma unroll
        for (int k = 0; k < 15; ++k) win[k] = vld[ci * 272 + tid + k];
#pragma unroll
        for (int k = 0; k < 15; ++k) {
            a0 = fmaf(p3w[ci * 15 + k], win[k], a0);         // o=0
            a1 = fmaf(p3w[480 + ci * 15 + k], win[k], a1);   // o=1
        }
    }
    const int t = t0 + tid;
    const float wt = sig_(a0);
    const float bm = sig_(a1);
    outw[b * TT + t] = wt;
    outbm[b * TT + t] = bm;
    moves[b * TT + t] = bm * nm[0];
}

// ---------------- Kernel 2: scan + coefs + lens + segment bounds ----------------
// 1024 threads/batch, float4/thread, 2 serial chunks. Writes, for every integer
// lf in [-1, LFULL]: bnd[b][lf+1] = lower_bound(poses >= lf)  (TT if none).
__global__ __launch_bounds__(1024) void k_scan(
    const float* __restrict__ moves, const float* __restrict__ wts,
    float* __restrict__ coef1, float* __restrict__ coef2,
    int* __restrict__ bnd, float* __restrict__ lens)
{
    __shared__ float wsum[16];
    const int tid = threadIdx.x;
    const int b = blockIdx.x;
    const int lane = tid & 63, wv = tid >> 6;
    float carry = 0.f;

    int* bb = &bnd[b * BSTRIDE];
    for (int i = tid; i < BSTRIDE; i += 1024) bb[i] = TT;   // default: no t reaches lf
    if (tid == 0) { bb[0] = 0; bb[1] = 0; }                 // lf <= 0 -> t = 0 (poses[0] > 0)
    __syncthreads();   // init must not race with crossing writes below

    const float4* mv4 = (const float4*)&moves[b * TT];
    const float4* wt4 = (const float4*)&wts[b * TT];
    float4* c14 = (float4*)&coef1[b * TT];
    float4* c24 = (float4*)&coef2[b * TT];

    for (int chunk = 0; chunk < 2; ++chunk) {
        const int idx = chunk * 1024 + tid;
        float4 m = mv4[idx];
        const float s = m.x + m.y + m.z + m.w;
        float v = s;
#pragma unroll
        for (int off = 1; off < 64; off <<= 1) {
            float n = __shfl_up(v, off, 64);
            if (lane >= off) v += n;
        }
        if (lane == 63) wsum[wv] = v;
        __syncthreads();
        float pre = carry;
        for (int w = 0; w < wv; ++w) pre += wsum[w];
        float tot = 0.f;
#pragma unroll
        for (int w = 0; w < 16; ++w) tot += wsum[w];
        const float base = pre + (v - s);       // exclusive prefix before this thread's 4
        const float p0 = base + m.x;
        const float p1 = p0 + m.y;
        const float p2 = p1 + m.z;
        const float p3 = p2 + m.w;
        const float4 w4 = wt4[idx];
        const float fr0 = p0 - floorf(p0), fr1 = p1 - floorf(p1);
        const float fr2 = p2 - floorf(p2), fr3 = p3 - floorf(p3);
        c14[idx] = make_float4((1.f - fr0) * w4.x, (1.f - fr1) * w4.y,
                               (1.f - fr2) * w4.z, (1.f - fr3) * w4.w);
        c24[idx] = make_float4(fr0 * w4.x, fr1 * w4.y, fr2 * w4.z, fr3 * w4.w);
        // integer crossings in (base, p3]: lower_bound index for each
        {
            int lf = (int)floorf(base) + 1;
            const int lfe = (int)floorf(p3);
            const int tbase = idx << 2;
            for (; lf <= lfe; ++lf) {
                const float lff = (float)lf;
                int t = tbase;
                if (p0 >= lff) { }
                else if (p1 >= lff) t += 1;
                else if (p2 >= lff) t += 2;
                else t += 3;
                if (lf + 1 < BSTRIDE) bb[lf + 1] = t;
            }
        }
        if (chunk == 1 && tid == 1023) lens[b] = floorf(p3) + 2.0f;
        carry += tot;
        __syncthreads();
    }
}

// ---------------- Kernel 2b: stream zeros over the inactive column range ----------------
// Inactive tiles satisfy l0 >= lens[b]; the boundary ACTIVE tile writes all its own
// columns (zero-padding its tail), so zeroing rows from ceil16(lens[b]) partitions exactly.
__global__ __launch_bounds__(256) void k_zero(
    const float* __restrict__ lens, float* __restrict__ xevs)
{
    const int b = blockIdx.y;
    const int cg = blockIdx.x;        // 4 channel rows per block
    const int zs = (((int)lens[b]) + 15) & ~15;
    if (zs >= LFULL) return;
    const int n4 = (LFULL - zs) >> 2; // zs, LFULL both multiples of 4
    const float4 z = make_float4(0.f, 0.f, 0.f, 0.f);
    for (int r = 0; r < 4; ++r) {
        float4* row4 = (float4*)&xevs[((size_t)(b * 256 + cg * 4 + r)) * LFULL + zs];
        for (int i = threadIdx.x; i < n4; i += 256) row4[i] = z;
    }
}

// ---------------- Kernel 3: fused GLU-features + CIF pooling (active tiles only) ----------------
static constexpr int LTILE = 32;
static constexpr int CHK = 128;

__global__ __launch_bounds__(256) void k_pool(
    const float* __restrict__ x,
    const float* __restrict__ cw,
    const float* __restrict__ bng, const float* __restrict__ bnb,
    const float* __restrict__ bnm, const float* __restrict__ bnv,
    const float* __restrict__ coef1, const float* __restrict__ coef2,
    const int* __restrict__ bnd,
    float* __restrict__ xevs)
{
    __shared__ float out_lds[256 * 33];     // [c][li], stride 33 (conflict-free)
    __shared__ float4 xl4[36];              // x window, chunk-staged (CHK+12 floats)
    __shared__ float4 c1l4[CHK / 4], c2l4[CHK / 4];
    __shared__ int lbs[LTILE + 2];
    float* xl = (float*)xl4;
    float* c1l = (float*)c1l4;
    float* c2l = (float*)c2l4;

    const int tid = threadIdx.x;
    const int b = blockIdx.y;
    const int l0 = blockIdx.x * LTILE;
    const int LTa = min(LTILE, LFULL - l0);

    if (tid < LTa + 2) lbs[tid] = bnd[b * BSTRIDE + l0 + tid];  // lf = l0-1+tid
    __syncthreads();

    const int t_lo = lbs[0];
    const int t_hi = lbs[LTa + 1];
    if (t_lo >= t_hi) return;   // inactive tile: k_zero covers it

    const size_t rowbase = (size_t)b * 256 * LFULL + l0;

    // zero own row (columns never emitted must read 0)
#pragma unroll
    for (int li = 0; li < 33; ++li) out_lds[tid * 33 + li] = 0.f;

    const int c = tid;
    float wa[9], wg[9];
#pragma unroll
    for (int k = 0; k < 9; ++k) { wa[k] = cw[c * 9 + k]; wg[k] = cw[(c + 256) * 9 + k]; }
    const float sa = bng[c] * rsqrtf(bnv[c] + 1e-3f);
    const float sha = bnb[c] - bnm[c] * sa;
    const float sg = bng[c + 256] * rsqrtf(bnv[c + 256] + 1e-3f);
    const float shg = bnb[c + 256] - bnm[c + 256] * sg;

    const float* xg = &x[b * TT];
    const float* c1g = &coef1[b * TT];
    const float* c2g = &coef2[b * TT];

    float accA = 0.f, accB = 0.f;   // accA: column j-1, accB: column j
    int j = 0;
    int nb = lbs[1];

    for (int cs = t_lo; cs < t_hi; cs += CHK) {
        const int ce = min(cs + CHK, t_hi);
        const int len = ce - cs;
        __syncthreads();           // previous chunk fully consumed
        for (int idx = tid; idx < len + 12; idx += 256) {
            int id = cs - 4 + idx;
            xl[idx] = (id >= 0 && id < TT) ? xg[id] : 0.f;
        }
        if (tid < len) { c1l[tid] = c1g[cs + tid]; c2l[tid] = c2g[cs + tid]; }
        __syncthreads();

        const int len4 = len >> 2;
        for (int g = 0; g < len4; ++g) {
            float4 A = xl4[g], Bq = xl4[g + 1], Cq = xl4[g + 2];
            float w[12] = {A.x, A.y, A.z, A.w, Bq.x, Bq.y, Bq.z, Bq.w, Cq.x, Cq.y, Cq.z, Cq.w};
            float f[4];
#pragma unroll
            for (int i = 0; i < 4; ++i) {
                float s0 = 0.f, s1 = 0.f;
#pragma unroll
                for (int k = 0; k < 9; ++k) { s0 = fmaf(wa[k], w[i + k], s0); s1 = fmaf(wg[k], w[i + k], s1); }
                const float av = fmaf(s0, sa, sha);
                const float gv = fmaf(s1, sg, shg);
                f[i] = av * sig_(gv);
            }
            float4 c1v = c1l4[g], c2v = c2l4[g];
            const float c1a[4] = {c1v.x, c1v.y, c1v.z, c1v.w};
            const float c2a[4] = {c2v.x, c2v.y, c2v.z, c2v.w};
            const int tb = cs + (g << 2);
#pragma unroll
            for (int i = 0; i < 4; ++i) {
                const int t = tb + i;
                while (t >= nb) {   // segment crossing(s)
                    int li = j - 1;
                    if (li >= 0 && li < LTa) out_lds[c * 33 + li] = accA;
                    accA = accB; accB = 0.f;
                    ++j;
                    nb = lbs[j + 1];
                }
                accA = fmaf(c1a[i], f[i], accA);
                accB = fmaf(c2a[i], f[i], accB);
            }
        }
        // tail (len not multiple of 4)
        for (int t = cs + (len4 << 2); t < ce; ++t) {
            const int il = t - cs;
            float s0 = 0.f, s1 = 0.f;
#pragma unroll
            for (int k = 0; k < 9; ++k) { float xv = xl[il + k]; s0 = fmaf(wa[k], xv, s0); s1 = fmaf(wg[k], xv, s1); }
            const float av = fmaf(s0, sa, sha);
            const float gv = fmaf(s1, sg, shg);
            const float f0 = av * sig_(gv);
            while (t >= nb) {
                int li = j - 1;
                if (li >= 0 && li < LTa) out_lds[c * 33 + li] = accA;
                accA = accB; accB = 0.f;
                ++j;
                nb = lbs[j + 1];
            }
            accA = fmaf(c1l[il], f0, accA);
            accB = fmaf(c2l[il], f0, accB);
        }
    }
    {   // trailing emit
        int li = j - 1;
        if (li >= 0 && li < LTa) out_lds[c * 33 + li] = accA;
    }
    __syncthreads();

#pragma unroll
    for (int it = 0; it < 8; ++it) {
        int idx4 = it * 256 + tid;
        int cc = idx4 >> 3, q = (idx4 & 7) << 2;
        if (q < LTa) {
            float4 o;
            o.x = out_lds[cc * 33 + q + 0];
            o.y = out_lds[cc * 33 + q + 1];
            o.z = out_lds[cc * 33 + q + 2];
            o.w = out_lds[cc * 33 + q + 3];
            *(float4*)(&xevs[rowbase + (size_t)cc * LFULL + q]) = o;
        }
    }
}

extern "C" void kernel_launch(void* const* d_in, const int* in_sizes, int n_in,
                              void* d_out, int out_size, void* d_ws, size_t ws_size,
                              hipStream_t stream) {
    (void)in_sizes; (void)n_in; (void)out_size; (void)ws_size;
    const float* x      = (const float*)d_in[0];
    const float* conv_w = (const float*)d_in[1];
    const float* bn_g   = (const float*)d_in[2];
    const float* bn_b   = (const float*)d_in[3];
    const float* bn_m   = (const float*)d_in[4];
    const float* bn_v   = (const float*)d_in[5];
    const float* p1_w   = (const float*)d_in[6];
    const float* p1_b   = (const float*)d_in[7];
    const float* pbn1_g = (const float*)d_in[8];
    const float* pbn1_b = (const float*)d_in[9];
    const float* pbn1_m = (const float*)d_in[10];
    const float* pbn1_v = (const float*)d_in[11];
    const float* p2_w   = (const float*)d_in[12];
    const float* p2_b   = (const float*)d_in[13];
    const float* pbn2_g = (const float*)d_in[14];
    const float* pbn2_b = (const float*)d_in[15];
    const float* pbn2_m = (const float*)d_in[16];
    const float* pbn2_v = (const float*)d_in[17];
    const float* p3_w   = (const float*)d_in[18];
    const float* p3_b   = (const float*)d_in[19];
    const float* nm     = (const float*)d_in[20];

    float* out = (float*)d_out;
    float* ws  = (float*)d_ws;
    float* u     = ws + U_OFF;
    float* v     = ws + V_OFF;
    float* moves = ws + MOVES_OFF;
    float* coef1 = ws + C1_OFF;
    float* coef2 = ws + C2_OFF;
    int*   bnd   = (int*)(ws + BND_OFF);   // overlays u — u is dead after k_conv2
    float* xevs  = out + XE_OFF;
    float* lens  = out + LENS_OFF;
    float* bmv   = out + BM_OFF;
    float* wts   = out + WT_OFF;

    k_conv1<<<dim3(32, 16), 256, 0, stream>>>(x, p1_w, p1_b, pbn1_g, pbn1_b, pbn1_m, pbn1_v, u);
    k_conv2<<<dim3(32, 16, 2), 256, 0, stream>>>(u, p2_w, p2_b, pbn2_g, pbn2_b, pbn2_m, pbn2_v, v);
    k_conv3<<<dim3(32, 16), 256, 0, stream>>>(v, p3_w, p3_b, nm, wts, bmv, moves);
    k_scan<<<16, 1024, 0, stream>>>(moves, wts, coef1, coef2, bnd, lens);
    k_zero<<<dim3(64, 16), 256, 0, stream>>>(lens, xevs);
    k_pool<<<dim3((LFULL + LTILE - 1) / LTILE, 16), 256, 0, stream>>>(
        x, conv_w, bn_g, bn_b, bn_m, bn_v, coef1, coef2, bnd, xevs);
}

// Round 6
// 339.373 us; speedup vs baseline: 1.1102x; 1.0486x over previous
//
#include <hip/hip_runtime.h>
#include <math.h>

// Problem constants
static constexpr int TT = 8192;          // sequence length
static constexpr int LFULL = 8196;       // Lmax (8194) + pad to mult of 3 (2)
static constexpr int BSTRIDE = LFULL + 2; // bounds per-batch stride (lf+1 for lf in [-1, LFULL])

// d_out layout (floats, concatenated in reference return order)
static constexpr size_t XE_OFF   = 0;                       // [16][256][8196]
static constexpr size_t LENS_OFF = (size_t)16*256*LFULL;
static constexpr size_t BM_OFF   = LENS_OFF + 16;           // bmoves [16][8192]
static constexpr size_t WT_OFF   = BM_OFF + (size_t)16*TT;  // weights [16][8192]

// ws layout (floats). bnd overlays u (u is dead after k_conv2; same-stream ordering).
static constexpr size_t U_OFF     = 0;                        // [16][32][8192]
static constexpr size_t V_OFF     = U_OFF + (size_t)16*32*TT; // [16][32][8192]
static constexpr size_t MOVES_OFF = V_OFF + (size_t)16*32*TT;
static constexpr size_t C1_OFF    = MOVES_OFF + (size_t)16*TT;
static constexpr size_t C2_OFF    = C1_OFF + (size_t)16*TT;
static constexpr size_t BND_OFF   = U_OFF;                    // int[16][BSTRIDE], 525 KB << 16.8 MB

__device__ __forceinline__ float sig_(float z) { return 1.0f / (1.0f + __expf(-z)); }

// ---------------- Kernel 1a: conv1 (2->32, k=31, pad15) + BN(1e-5) + swish -> u ----------------
__global__ __launch_bounds__(256) void k_conv1(
    const float* __restrict__ x,
    const float* __restrict__ p1w, const float* __restrict__ p1b,
    const float* __restrict__ g1, const float* __restrict__ b1,
    const float* __restrict__ m1, const float* __restrict__ v1,
    float* __restrict__ u)
{
    __shared__ float xin[2 * 320];   // [ci][xl], xl -> t0-15+xl, valid xl<286
    __shared__ float w1t[2 * 992];   // [ci][c*31+k]
    const int tid = threadIdx.x;
    const int b = blockIdx.y;
    const int t0 = blockIdx.x * 256;

    for (int idx = tid; idx < 640; idx += 256) {
        int ci = idx / 320, xl = idx - ci * 320;
        int id = t0 - 15 + xl;
        float val = 0.f;
        if (xl < 286 && id >= 0 && id < TT) val = x[b * TT + id];
        xin[idx] = ci ? val * val : val;   // predictor input = cat([x, x*x])
    }
    for (int idx = tid; idx < 1984; idx += 256) {
        int c = idx / 62; int r = idx - c * 62; int ci = r / 31; int k = r - ci * 31;
        w1t[ci * 992 + c * 31 + k] = p1w[idx];
    }
    __syncthreads();

    const int tg = tid >> 5, c = tid & 31;
    float acc[32];
    const float bias = p1b[c];
#pragma unroll
    for (int i = 0; i < 32; ++i) acc[i] = bias;

    for (int h = 0; h < 4; ++h) {
        for (int ci = 0; ci < 2; ++ci) {
            float win[40];
            const float4* wp = (const float4*)(&xin[ci * 320 + tg * 32 + h * 8]);
#pragma unroll
            for (int r = 0; r < 10; ++r) {
                float4 q = wp[r];
                win[4*r] = q.x; win[4*r+1] = q.y; win[4*r+2] = q.z; win[4*r+3] = q.w;
            }
#pragma unroll
            for (int k = 0; k < 31; ++k) {
                float w = w1t[ci * 992 + c * 31 + k];
#pragma unroll
                for (int i = 0; i < 8; ++i) acc[h*8+i] = fmaf(w, win[i + k], acc[h*8+i]);
            }
        }
    }
    const float s = g1[c] * rsqrtf(v1[c] + 1e-5f);
    const float sh = b1[c] - m1[c] * s;
    float* up = &u[((size_t)(b * 32 + c)) * TT + t0 + tg * 32];
#pragma unroll
    for (int i = 0; i < 8; ++i) {
        float z0 = fmaf(acc[4*i+0], s, sh);
        float z1 = fmaf(acc[4*i+1], s, sh);
        float z2 = fmaf(acc[4*i+2], s, sh);
        float z3 = fmaf(acc[4*i+3], s, sh);
        ((float4*)up)[i] = make_float4(z0 * sig_(z0), z1 * sig_(z1), z2 * sig_(z2), z3 * sig_(z3));
    }
}

// ---------------- Kernel 1b: conv2 (32->32, k=15, pad7) + BN(1e-5) + swish -> v ----------------
// 16 t per thread, 256-t tiles, ci split in two staged halves, weights padded to 16 for b128.
__global__ __launch_bounds__(256) void k_conv2(
    const float* __restrict__ u,
    const float* __restrict__ p2w, const float* __restrict__ p2b,
    const float* __restrict__ g2, const float* __restrict__ b2,
    const float* __restrict__ m2, const float* __restrict__ v2,
    float* __restrict__ vout)
{
    __shared__ float uld[16 * 272];   // [ci][tl], tl -> t0-7+tl, valid tl<270
    __shared__ float w2t[16 * 256];   // [ci][cl*16+k], k=15 zero-padded
    const int tid = threadIdx.x;
    const int b = blockIdx.y;
    const int t0 = blockIdx.x * 256;
    const int ch = blockIdx.z;        // c-half: c = ch*16 + cl

    const int tg = tid >> 4, cl = tid & 15;
    const int c = ch * 16 + cl;
    float acc[16];
    const float bias = p2b[c];
#pragma unroll
    for (int i = 0; i < 16; ++i) acc[i] = bias;

    for (int h = 0; h < 2; ++h) {
        __syncthreads();   // previous half fully consumed
        for (int idx = tid; idx < 16 * 272; idx += 256) {
            int ci = idx / 272, tl = idx - ci * 272;
            int tgl = t0 - 7 + tl;
            float val = 0.f;
            if (tl < 270 && tgl >= 0 && tgl < TT) val = u[((size_t)(b * 32 + h * 16 + ci)) * TT + tgl];
            uld[idx] = val;
        }
        for (int idx = tid; idx < 16 * 256; idx += 256) {
            int ci = idx >> 8; int r = idx & 255; int cl2 = r >> 4; int k = r & 15;
            w2t[idx] = (k < 15) ? p2w[(ch * 16 + cl2) * 480 + (h * 16 + ci) * 15 + k] : 0.f;
        }
        __syncthreads();

        for (int ci = 0; ci < 16; ++ci) {
            float win[32];
            const float4* wp = (const float4*)(&uld[ci * 272 + tg * 16]);
#pragma unroll
            for (int r = 0; r < 8; ++r) {
                float4 q = wp[r];
                win[4*r] = q.x; win[4*r+1] = q.y; win[4*r+2] = q.z; win[4*r+3] = q.w;
            }
            float w[16];
            const float4* wqp = (const float4*)(&w2t[ci * 256 + cl * 16]);
#pragma unroll
            for (int r = 0; r < 4; ++r) {
                float4 q = wqp[r];
                w[4*r] = q.x; w[4*r+1] = q.y; w[4*r+2] = q.z; w[4*r+3] = q.w;
            }
#pragma unroll
            for (int k = 0; k < 15; ++k) {
#pragma unroll
                for (int i = 0; i < 16; ++i) acc[i] = fmaf(w[k], win[i + k], acc[i]);
            }
        }
    }
    const float s = g2[c] * rsqrtf(v2[c] + 1e-5f);
    const float sh = b2[c] - m2[c] * s;
    float o[16];
#pragma unroll
    for (int i = 0; i < 16; ++i) { float z = fmaf(acc[i], s, sh); o[i] = z * sig_(z); }
    float* vp = &vout[((size_t)(b * 32 + c)) * TT + t0 + tg * 16];
#pragma unroll
    for (int r = 0; r < 4; ++r)
        ((float4*)vp)[r] = make_float4(o[4*r], o[4*r+1], o[4*r+2], o[4*r+3]);
}

// ---------------- Kernel 1c: conv3 (32->2, k=15, pad7) + sigmoids ----------------
// 4-t groups split over 4 threads (8 ci each): b128 LDS reads + shfl reduction.
__global__ __launch_bounds__(256) void k_conv3(
    const float* __restrict__ vin,
    const float* __restrict__ p3w, const float* __restrict__ p3b,
    const float* __restrict__ nm,
    float* __restrict__ outw, float* __restrict__ outbm, float* __restrict__ moves)
{
    __shared__ float vld[32 * 276];   // stride 276: 16B-aligned rows, bank-spread
    __shared__ float wsh[960];        // p3w staged: [o][ci][15]
    const int tid = threadIdx.x;
    const int b = blockIdx.y;
    const int t0 = blockIdx.x * 256;

    for (int idx = tid; idx < 32 * 272; idx += 256) {
        int ci = idx / 272, tl = idx - ci * 272;
        int tg = t0 - 7 + tl;
        float val = 0.f;
        if (tl < 270 && tg >= 0 && tg < TT) val = vin[((size_t)(b * 32 + ci)) * TT + tg];
        vld[ci * 276 + tl] = val;
    }
    for (int idx = tid; idx < 960; idx += 256) wsh[idx] = p3w[idx];
    __syncthreads();

    const int g = tid >> 2;   // t-group: t = t0 + 4g + {0..3}
    const int q = tid & 3;    // ci subset: ci = q + 4*i
    float acc[8];             // [out0 t0..3 | out1 t0..3]
#pragma unroll
    for (int i = 0; i < 8; ++i) acc[i] = 0.f;

#pragma unroll
    for (int i = 0; i < 8; ++i) {
        const int ci = q + 4 * i;
        float win[20];
        const float4* wp = (const float4*)(&vld[ci * 276 + g * 4]);
#pragma unroll
        for (int r = 0; r < 5; ++r) {
            float4 v4 = wp[r];
            win[4*r] = v4.x; win[4*r+1] = v4.y; win[4*r+2] = v4.z; win[4*r+3] = v4.w;
        }
        const float* w0 = &wsh[ci * 15];
        const float* w1 = &wsh[480 + ci * 15];
#pragma unroll
        for (int k = 0; k < 15; ++k) {
            const float a = w0[k], gw = w1[k];
#pragma unroll
            for (int tt = 0; tt < 4; ++tt) {
                acc[tt]     = fmaf(a,  win[k + tt], acc[tt]);
                acc[4 + tt] = fmaf(gw, win[k + tt], acc[4 + tt]);
            }
        }
    }
#pragma unroll
    for (int i = 0; i < 8; ++i) {
        acc[i] += __shfl_xor(acc[i], 1, 64);
        acc[i] += __shfl_xor(acc[i], 2, 64);
    }
    if (q == 0) {
        const float nmv = nm[0];
        const float b0 = p3b[0], b1 = p3b[1];
        const int t = t0 + g * 4;
        float4 wv = make_float4(sig_(acc[0]+b0), sig_(acc[1]+b0), sig_(acc[2]+b0), sig_(acc[3]+b0));
        float4 bm = make_float4(sig_(acc[4]+b1), sig_(acc[5]+b1), sig_(acc[6]+b1), sig_(acc[7]+b1));
        float4 mv = make_float4(bm.x*nmv, bm.y*nmv, bm.z*nmv, bm.w*nmv);
        *(float4*)&outw[b * TT + t]  = wv;
        *(float4*)&outbm[b * TT + t] = bm;
        *(float4*)&moves[b * TT + t] = mv;
    }
}

// ---------------- Kernel 2: scan + coefs + lens + segment bounds ----------------
__global__ __launch_bounds__(1024) void k_scan(
    const float* __restrict__ moves, const float* __restrict__ wts,
    float* __restrict__ coef1, float* __restrict__ coef2,
    int* __restrict__ bnd, float* __restrict__ lens)
{
    __shared__ float wsum[16];
    const int tid = threadIdx.x;
    const int b = blockIdx.x;
    const int lane = tid & 63, wv = tid >> 6;
    float carry = 0.f;

    int* bb = &bnd[b * BSTRIDE];
    for (int i = tid; i < BSTRIDE; i += 1024) bb[i] = TT;   // default: no t reaches lf
    if (tid == 0) { bb[0] = 0; bb[1] = 0; }                 // lf <= 0 -> t = 0 (poses[0] > 0)
    __syncthreads();   // init must not race with crossing writes below

    const float4* mv4 = (const float4*)&moves[b * TT];
    const float4* wt4 = (const float4*)&wts[b * TT];
    float4* c14 = (float4*)&coef1[b * TT];
    float4* c24 = (float4*)&coef2[b * TT];

    for (int chunk = 0; chunk < 2; ++chunk) {
        const int idx = chunk * 1024 + tid;
        float4 m = mv4[idx];
        const float s = m.x + m.y + m.z + m.w;
        float v = s;
#pragma unroll
        for (int off = 1; off < 64; off <<= 1) {
            float n = __shfl_up(v, off, 64);
            if (lane >= off) v += n;
        }
        if (lane == 63) wsum[wv] = v;
        __syncthreads();
        float pre = carry;
        for (int w = 0; w < wv; ++w) pre += wsum[w];
        float tot = 0.f;
#pragma unroll
        for (int w = 0; w < 16; ++w) tot += wsum[w];
        const float base = pre + (v - s);       // exclusive prefix before this thread's 4
        const float p0 = base + m.x;
        const float p1 = p0 + m.y;
        const float p2 = p1 + m.z;
        const float p3 = p2 + m.w;
        const float4 w4 = wt4[idx];
        const float fr0 = p0 - floorf(p0), fr1 = p1 - floorf(p1);
        const float fr2 = p2 - floorf(p2), fr3 = p3 - floorf(p3);
        c14[idx] = make_float4((1.f - fr0) * w4.x, (1.f - fr1) * w4.y,
                               (1.f - fr2) * w4.z, (1.f - fr3) * w4.w);
        c24[idx] = make_float4(fr0 * w4.x, fr1 * w4.y, fr2 * w4.z, fr3 * w4.w);
        // integer crossings in (base, p3]: lower_bound index for each
        {
            int lf = (int)floorf(base) + 1;
            const int lfe = (int)floorf(p3);
            const int tbase = idx << 2;
            for (; lf <= lfe; ++lf) {
                const float lff = (float)lf;
                int t = tbase;
                if (p0 >= lff) { }
                else if (p1 >= lff) t += 1;
                else if (p2 >= lff) t += 2;
                else t += 3;
                if (lf + 1 < BSTRIDE) bb[lf + 1] = t;
            }
        }
        if (chunk == 1 && tid == 1023) lens[b] = floorf(p3) + 2.0f;
        carry += tot;
        __syncthreads();
    }
}

// ---------------- Kernel 3: fused GLU-features + CIF pooling + zero-fill ----------------
// Block roles by blockIdx.x: [0, NPOOLX) pool tiles; [NPOOLX, NPOOLX+64) zero-stream
// over the inactive column range (l >= ceil16(lens[b]), 4 rows per block, linear writes).
static constexpr int LTILE = 32;
static constexpr int CHK = 256;
static constexpr int NPOOLX = (LFULL + LTILE - 1) / LTILE;  // 257

__global__ __launch_bounds__(256) void k_pool(
    const float* __restrict__ x,
    const float* __restrict__ cw,
    const float* __restrict__ bng, const float* __restrict__ bnb,
    const float* __restrict__ bnm, const float* __restrict__ bnv,
    const float* __restrict__ coef1, const float* __restrict__ coef2,
    const int* __restrict__ bnd, const float* __restrict__ lens,
    float* __restrict__ xevs)
{
    __shared__ float out_lds[256 * 33];     // [c][li], stride 33 (conflict-free)
    __shared__ float4 xl4[68];              // x window, chunk-staged (CHK+12 floats)
    __shared__ float4 c1l4[CHK / 4], c2l4[CHK / 4];
    __shared__ int lbs[LTILE + 2];
    float* xl = (float*)xl4;
    float* c1l = (float*)c1l4;
    float* c2l = (float*)c2l4;

    const int tid = threadIdx.x;
    const int b = blockIdx.y;

    if (blockIdx.x >= NPOOLX) {   // zero role
        const int zx = blockIdx.x - NPOOLX;       // 0..63, 4 rows each
        const int zs = (((int)lens[b]) + 15) & ~15;
        if (zs >= LFULL) return;
        const int n4 = (LFULL - zs) >> 2;
        const float4 z = make_float4(0.f, 0.f, 0.f, 0.f);
        for (int r = 0; r < 4; ++r) {
            float4* row4 = (float4*)&xevs[((size_t)(b * 256 + zx * 4 + r)) * LFULL + zs];
            for (int i = tid; i < n4; i += 256) row4[i] = z;
        }
        return;
    }

    const int l0 = blockIdx.x * LTILE;
    const int LTa = min(LTILE, LFULL - l0);

    if (tid < LTa + 2) lbs[tid] = bnd[b * BSTRIDE + l0 + tid];  // lf = l0-1+tid
    __syncthreads();

    const int t_lo = lbs[0];
    const int t_hi = lbs[LTa + 1];
    if (t_lo >= t_hi) return;   // inactive tile: zero role covers it

    const size_t rowbase = (size_t)b * 256 * LFULL + l0;

    // zero own row (columns never emitted must read 0)
#pragma unroll
    for (int li = 0; li < 33; ++li) out_lds[tid * 33 + li] = 0.f;

    const int c = tid;
    float wa[9], wg[9];
#pragma unroll
    for (int k = 0; k < 9; ++k) { wa[k] = cw[c * 9 + k]; wg[k] = cw[(c + 256) * 9 + k]; }
    const float sa = bng[c] * rsqrtf(bnv[c] + 1e-3f);
    const float sha = bnb[c] - bnm[c] * sa;
    const float sg = bng[c + 256] * rsqrtf(bnv[c + 256] + 1e-3f);
    const float shg = bnb[c + 256] - bnm[c + 256] * sg;

    const float* xg = &x[b * TT];
    const float* c1g = &coef1[b * TT];
    const float* c2g = &coef2[b * TT];

    float accA = 0.f, accB = 0.f;   // accA: column j-1, accB: column j
    int j = 0;
    int nb = lbs[1];

    for (int cs = t_lo; cs < t_hi; cs += CHK) {
        const int ce = min(cs + CHK, t_hi);
        const int len = ce - cs;
        __syncthreads();           // previous chunk fully consumed
        for (int idx = tid; idx < len + 12; idx += 256) {
            int id = cs - 4 + idx;
            xl[idx] = (id >= 0 && id < TT) ? xg[id] : 0.f;
        }
        if (tid < len) { c1l[tid] = c1g[cs + tid]; c2l[tid] = c2g[cs + tid]; }
        __syncthreads();

        const int len4 = len >> 2;
        for (int g = 0; g < len4; ++g) {
            float4 A = xl4[g], Bq = xl4[g + 1], Cq = xl4[g + 2];
            float w[12] = {A.x, A.y, A.z, A.w, Bq.x, Bq.y, Bq.z, Bq.w, Cq.x, Cq.y, Cq.z, Cq.w};
            float f[4];
#pragma unroll
            for (int i = 0; i < 4; ++i) {
                float s0 = 0.f, s1 = 0.f;
#pragma unroll
                for (int k = 0; k < 9; ++k) { s0 = fmaf(wa[k], w[i + k], s0); s1 = fmaf(wg[k], w[i + k], s1); }
                const float av = fmaf(s0, sa, sha);
                const float gv = fmaf(s1, sg, shg);
                f[i] = av * sig_(gv);
            }
            float4 c1v = c1l4[g], c2v = c2l4[g];
            const float c1a[4] = {c1v.x, c1v.y, c1v.z, c1v.w};
            const float c2a[4] = {c2v.x, c2v.y, c2v.z, c2v.w};
            const int tb = cs + (g << 2);
#pragma unroll
            for (int i = 0; i < 4; ++i) {
                const int t = tb + i;
                while (t >= nb) {   // segment crossing(s)
                    int li = j - 1;
                    if (li >= 0 && li < LTa) out_lds[c * 33 + li] = accA;
                    accA = accB; accB = 0.f;
                    ++j;
                    nb = lbs[j + 1];
                }
                accA = fmaf(c1a[i], f[i], accA);
                accB = fmaf(c2a[i], f[i], accB);
            }
        }
        // tail (len not multiple of 4)
        for (int t = cs + (len4 << 2); t < ce; ++t) {
            const int il = t - cs;
            float s0 = 0.f, s1 = 0.f;
#pragma unroll
            for (int k = 0; k < 9; ++k) { float xv = xl[il + k]; s0 = fmaf(wa[k], xv, s0); s1 = fmaf(wg[k], xv, s1); }
            const float av = fmaf(s0, sa, sha);
            const float gv = fmaf(s1, sg, shg);
            const float f0 = av * sig_(gv);
            while (t >= nb) {
                int li = j - 1;
                if (li >= 0 && li < LTa) out_lds[c * 33 + li] = accA;
                accA = accB; accB = 0.f;
                ++j;
                nb = lbs[j + 1];
            }
            accA = fmaf(c1l[il], f0, accA);
            accB = fmaf(c2l[il], f0, accB);
        }
    }
    {   // trailing emit
        int li = j - 1;
        if (li >= 0 && li < LTa) out_lds[c * 33 + li] = accA;
    }
    __syncthreads();

#pragma unroll
    for (int it = 0; it < 8; ++it) {
        int idx4 = it * 256 + tid;
        int cc = idx4 >> 3, q = (idx4 & 7) << 2;
        if (q < LTa) {
            float4 o;
            o.x = out_lds[cc * 33 + q + 0];
            o.y = out_lds[cc * 33 + q + 1];
            o.z = out_lds[cc * 33 + q + 2];
            o.w = out_lds[cc * 33 + q + 3];
            *(float4*)(&xevs[rowbase + (size_t)cc * LFULL + q]) = o;
        }
    }
}

extern "C" void kernel_launch(void* const* d_in, const int* in_sizes, int n_in,
                              void* d_out, int out_size, void* d_ws, size_t ws_size,
                              hipStream_t stream) {
    (void)in_sizes; (void)n_in; (void)out_size; (void)ws_size;
    const float* x      = (const float*)d_in[0];
    const float* conv_w = (const float*)d_in[1];
    const float* bn_g   = (const float*)d_in[2];
    const float* bn_b   = (const float*)d_in[3];
    const float* bn_m   = (const float*)d_in[4];
    const float* bn_v   = (const float*)d_in[5];
    const float* p1_w   = (const float*)d_in[6];
    const float* p1_b   = (const float*)d_in[7];
    const float* pbn1_g = (const float*)d_in[8];
    const float* pbn1_b = (const float*)d_in[9];
    const float* pbn1_m = (const float*)d_in[10];
    const float* pbn1_v = (const float*)d_in[11];
    const float* p2_w   = (const float*)d_in[12];
    const float* p2_b   = (const float*)d_in[13];
    const float* pbn2_g = (const float*)d_in[14];
    const float* pbn2_b = (const float*)d_in[15];
    const float* pbn2_m = (const float*)d_in[16];
    const float* pbn2_v = (const float*)d_in[17];
    const float* p3_w   = (const float*)d_in[18];
    const float* p3_b   = (const float*)d_in[19];
    const float* nm     = (const float*)d_in[20];

    float* out = (float*)d_out;
    float* ws  = (float*)d_ws;
    float* u     = ws + U_OFF;
    float* v     = ws + V_OFF;
    float* moves = ws + MOVES_OFF;
    float* coef1 = ws + C1_OFF;
    float* coef2 = ws + C2_OFF;
    int*   bnd   = (int*)(ws + BND_OFF);   // overlays u — u is dead after k_conv2
    float* xevs  = out + XE_OFF;
    float* lens  = out + LENS_OFF;
    float* bmv   = out + BM_OFF;
    float* wts   = out + WT_OFF;

    k_conv1<<<dim3(32, 16), 256, 0, stream>>>(x, p1_w, p1_b, pbn1_g, pbn1_b, pbn1_m, pbn1_v, u);
    k_conv2<<<dim3(32, 16, 2), 256, 0, stream>>>(u, p2_w, p2_b, pbn2_g, pbn2_b, pbn2_m, pbn2_v, v);
    k_conv3<<<dim3(32, 16), 256, 0, stream>>>(v, p3_w, p3_b, nm, wts, bmv, moves);
    k_scan<<<16, 1024, 0, stream>>>(moves, wts, coef1, coef2, bnd, lens);
    k_pool<<<dim3(NPOOLX + 64, 16), 256, 0, stream>>>(
        x, conv_w, bn_g, bn_b, bn_m, bn_v, coef1, coef2, bnd, lens, xevs);
}

// Round 7
// 337.030 us; speedup vs baseline: 1.1179x; 1.0070x over previous
//
#include <hip/hip_runtime.h>
#include <math.h>

// Problem constants
static constexpr int TT = 8192;          // sequence length
static constexpr int LFULL = 8196;       // Lmax (8194) + pad to mult of 3 (2)
static constexpr int BSTRIDE = LFULL + 2; // bounds per-batch stride (lf+1 for lf in [-1, LFULL])

// d_out layout (floats, concatenated in reference return order)
static constexpr size_t XE_OFF   = 0;                       // [16][256][8196]
static constexpr size_t LENS_OFF = (size_t)16*256*LFULL;
static constexpr size_t BM_OFF   = LENS_OFF + 16;           // bmoves [16][8192]
static constexpr size_t WT_OFF   = BM_OFF + (size_t)16*TT;  // weights [16][8192]

// ws layout (floats). bnd overlays the (now unused) U region.
static constexpr size_t U_OFF     = 0;
static constexpr size_t V_OFF     = U_OFF + (size_t)16*32*TT; // [16][32][8192]
static constexpr size_t MOVES_OFF = V_OFF + (size_t)16*32*TT;
static constexpr size_t C1_OFF    = MOVES_OFF + (size_t)16*TT;
static constexpr size_t C2_OFF    = C1_OFF + (size_t)16*TT;
static constexpr size_t BND_OFF   = U_OFF;                    // int[16][BSTRIDE]

__device__ __forceinline__ float sig_(float z) { return 1.0f / (1.0f + __expf(-z)); }

typedef float f4v __attribute__((ext_vector_type(4)));
__device__ __forceinline__ void nt_store4(float* p, float a, float b, float c, float d) {
    f4v v = {a, b, c, d};
    __builtin_nontemporal_store(v, (f4v*)p);
}

// ---------------- Kernel 1: fused conv1(2->32,k=31) + BN + swish + conv2(32->32,k=15) + BN + swish -> v
// Per block: 256 t outputs for 16 out-channels (z = half). u lives only in LDS.
__global__ __launch_bounds__(256) void k_conv12(
    const float* __restrict__ x,
    const float* __restrict__ p1w, const float* __restrict__ p1b,
    const float* __restrict__ g1, const float* __restrict__ b1,
    const float* __restrict__ m1, const float* __restrict__ v1,
    const float* __restrict__ p2w, const float* __restrict__ p2b,
    const float* __restrict__ g2, const float* __restrict__ b2,
    const float* __restrict__ m2, const float* __restrict__ v2,
    float* __restrict__ vout)
{
    __shared__ float xin[320];        // x[t0-22 .. t0+297]
    __shared__ float w1t[2 * 992];    // [ci][c*31+k]
    __shared__ float uld[32 * 276];   // u(t0-7+tl), tl in [0,270); stride 276 (4-align, bank-spread)
    __shared__ float w2t[32 * 256];   // [ci][cl*16+k], k=15 zero-padded; this half's out-channels
    const int tid = threadIdx.x;
    const int b = blockIdx.y;
    const int t0 = blockIdx.x * 256;
    const int ch = blockIdx.z;

    for (int idx = tid; idx < 320; idx += 256) {
        int id = t0 - 22 + idx;
        xin[idx] = (id >= 0 && id < TT) ? x[b * TT + id] : 0.f;
    }
    for (int idx = tid; idx < 1984; idx += 256) {
        int c = idx / 62; int r = idx - c * 62; int ci = r / 31; int k = r - ci * 31;
        w1t[ci * 992 + c * 31 + k] = p1w[idx];
    }
    for (int idx = tid; idx < 32 * 256; idx += 256) {
        int ci = idx >> 8; int r = idx & 255; int cl2 = r >> 4; int k = r & 15;
        w2t[idx] = (k < 15) ? p2w[(ch * 16 + cl2) * 480 + ci * 15 + k] : 0.f;
    }
    __syncthreads();

    // ---- Stage B: conv1 + BN1 + swish -> uld (each thread: channel cB, 36 positions) ----
    {
        const int cB = tid & 31, pg = tid >> 5;
        const float s1v = g1[cB] * rsqrtf(v1[cB] + 1e-5f);
        const float sh1 = b1[cB] - m1[cB] * s1v;
        const float bias1 = p1b[cB];
        const int base = pg * 36;
        const float* wA = &w1t[cB * 31];
        const float* wB = &w1t[992 + cB * 31];
#pragma unroll
        for (int h = 0; h < 5; ++h) {
            const int off = h * 8;                 // 0,8,16,24,32
            const int len = (h < 4) ? 8 : 4;
            const int nld = (h < 4) ? 10 : 9;
            float win[40], wsq[40];
            const float4* xp = (const float4*)(&xin[base + off]);
            for (int r = 0; r < nld; ++r) {
                float4 q = xp[r];
                win[4*r] = q.x; win[4*r+1] = q.y; win[4*r+2] = q.z; win[4*r+3] = q.w;
            }
            for (int i = 0; i < 4 * nld; ++i) wsq[i] = win[i] * win[i];
            float acc[8];
#pragma unroll
            for (int i = 0; i < 8; ++i) acc[i] = bias1;
#pragma unroll
            for (int k = 0; k < 31; ++k) {
                const float a = wA[k], bw = wB[k];
                for (int i = 0; i < len; ++i) {
                    acc[i] = fmaf(a, win[i + k], acc[i]);
                    acc[i] = fmaf(bw, wsq[i + k], acc[i]);
                }
            }
            for (int i = 0; i < len; ++i) {
                const int tl = base + off + i;
                if (tl < 270) {
                    const float z = fmaf(acc[i], s1v, sh1);
                    uld[cB * 276 + tl] = z * sig_(z);
                }
            }
        }
    }
    __syncthreads();

    // ---- Stage C: conv2 + BN2 + swish -> v (each thread: out-channel c2, 16 t) ----
    const int tg = tid >> 4, cl = tid & 15;
    const int c2 = ch * 16 + cl;
    float acc2[16];
    const float bias2 = p2b[c2];
#pragma unroll
    for (int i = 0; i < 16; ++i) acc2[i] = bias2;

    for (int ci = 0; ci < 32; ++ci) {
        float win[32];
        const float4* wp = (const float4*)(&uld[ci * 276 + tg * 16]);
#pragma unroll
        for (int r = 0; r < 8; ++r) {
            float4 q = wp[r];
            win[4*r] = q.x; win[4*r+1] = q.y; win[4*r+2] = q.z; win[4*r+3] = q.w;
        }
        float w[16];
        const float4* wqp = (const float4*)(&w2t[ci * 256 + cl * 16]);
#pragma unroll
        for (int r = 0; r < 4; ++r) {
            float4 q = wqp[r];
            w[4*r] = q.x; w[4*r+1] = q.y; w[4*r+2] = q.z; w[4*r+3] = q.w;
        }
#pragma unroll
        for (int k = 0; k < 15; ++k) {
#pragma unroll
            for (int i = 0; i < 16; ++i) acc2[i] = fmaf(w[k], win[i + k], acc2[i]);
        }
    }
    const float s = g2[c2] * rsqrtf(v2[c2] + 1e-5f);
    const float sh = b2[c2] - m2[c2] * s;
    float o[16];
#pragma unroll
    for (int i = 0; i < 16; ++i) { float z = fmaf(acc2[i], s, sh); o[i] = z * sig_(z); }
    float* vp = &vout[((size_t)(b * 32 + c2)) * TT + t0 + tg * 16];
#pragma unroll
    for (int r = 0; r < 4; ++r)
        ((float4*)vp)[r] = make_float4(o[4*r], o[4*r+1], o[4*r+2], o[4*r+3]);
}

// ---------------- Kernel 1c: conv3 (32->2, k=15, pad7) + sigmoids ----------------
// 4-t groups split over 4 threads (8 ci each): b128 LDS reads + shfl reduction.
__global__ __launch_bounds__(256) void k_conv3(
    const float* __restrict__ vin,
    const float* __restrict__ p3w, const float* __restrict__ p3b,
    const float* __restrict__ nm,
    float* __restrict__ outw, float* __restrict__ outbm, float* __restrict__ moves)
{
    __shared__ float vld[32 * 276];   // stride 276: 16B-aligned rows, bank-spread
    __shared__ float wsh[960];        // p3w staged: [o][ci][15]
    const int tid = threadIdx.x;
    const int b = blockIdx.y;
    const int t0 = blockIdx.x * 256;

    for (int idx = tid; idx < 32 * 272; idx += 256) {
        int ci = idx / 272, tl = idx - ci * 272;
        int tg = t0 - 7 + tl;
        float val = 0.f;
        if (tl < 270 && tg >= 0 && tg < TT) val = vin[((size_t)(b * 32 + ci)) * TT + tg];
        vld[ci * 276 + tl] = val;
    }
    for (int idx = tid; idx < 960; idx += 256) wsh[idx] = p3w[idx];
    __syncthreads();

    const int g = tid >> 2;   // t-group: t = t0 + 4g + {0..3}
    const int q = tid & 3;    // ci subset: ci = q + 4*i
    float acc[8];             // [out0 t0..3 | out1 t0..3]
#pragma unroll
    for (int i = 0; i < 8; ++i) acc[i] = 0.f;

#pragma unroll
    for (int i = 0; i < 8; ++i) {
        const int ci = q + 4 * i;
        float win[20];
        const float4* wp = (const float4*)(&vld[ci * 276 + g * 4]);
#pragma unroll
        for (int r = 0; r < 5; ++r) {
            float4 v4 = wp[r];
            win[4*r] = v4.x; win[4*r+1] = v4.y; win[4*r+2] = v4.z; win[4*r+3] = v4.w;
        }
        const float* w0 = &wsh[ci * 15];
        const float* w1 = &wsh[480 + ci * 15];
#pragma unroll
        for (int k = 0; k < 15; ++k) {
            const float a = w0[k], gw = w1[k];
#pragma unroll
            for (int tt = 0; tt < 4; ++tt) {
                acc[tt]     = fmaf(a,  win[k + tt], acc[tt]);
                acc[4 + tt] = fmaf(gw, win[k + tt], acc[4 + tt]);
            }
        }
    }
#pragma unroll
    for (int i = 0; i < 8; ++i) {
        acc[i] += __shfl_xor(acc[i], 1, 64);
        acc[i] += __shfl_xor(acc[i], 2, 64);
    }
    if (q == 0) {
        const float nmv = nm[0];
        const float b0 = p3b[0], b1 = p3b[1];
        const int t = t0 + g * 4;
        float4 wv = make_float4(sig_(acc[0]+b0), sig_(acc[1]+b0), sig_(acc[2]+b0), sig_(acc[3]+b0));
        float4 bm = make_float4(sig_(acc[4]+b1), sig_(acc[5]+b1), sig_(acc[6]+b1), sig_(acc[7]+b1));
        float4 mv = make_float4(bm.x*nmv, bm.y*nmv, bm.z*nmv, bm.w*nmv);
        *(float4*)&outw[b * TT + t]  = wv;
        *(float4*)&outbm[b * TT + t] = bm;
        *(float4*)&moves[b * TT + t] = mv;
    }
}

// ---------------- Kernel 2: scan + coefs + lens + segment bounds ----------------
__global__ __launch_bounds__(1024) void k_scan(
    const float* __restrict__ moves, const float* __restrict__ wts,
    float* __restrict__ coef1, float* __restrict__ coef2,
    int* __restrict__ bnd, float* __restrict__ lens)
{
    __shared__ float wsum[16];
    const int tid = threadIdx.x;
    const int b = blockIdx.x;
    const int lane = tid & 63, wv = tid >> 6;
    float carry = 0.f;

    int* bb = &bnd[b * BSTRIDE];
    for (int i = tid; i < BSTRIDE; i += 1024) bb[i] = TT;   // default: no t reaches lf
    if (tid == 0) { bb[0] = 0; bb[1] = 0; }                 // lf <= 0 -> t = 0 (poses[0] > 0)
    __syncthreads();   // init must not race with crossing writes below

    const float4* mv4 = (const float4*)&moves[b * TT];
    const float4* wt4 = (const float4*)&wts[b * TT];
    float4* c14 = (float4*)&coef1[b * TT];
    float4* c24 = (float4*)&coef2[b * TT];

    for (int chunk = 0; chunk < 2; ++chunk) {
        const int idx = chunk * 1024 + tid;
        float4 m = mv4[idx];
        const float s = m.x + m.y + m.z + m.w;
        float v = s;
#pragma unroll
        for (int off = 1; off < 64; off <<= 1) {
            float n = __shfl_up(v, off, 64);
            if (lane >= off) v += n;
        }
        if (lane == 63) wsum[wv] = v;
        __syncthreads();
        float pre = carry;
        for (int w = 0; w < wv; ++w) pre += wsum[w];
        float tot = 0.f;
#pragma unroll
        for (int w = 0; w < 16; ++w) tot += wsum[w];
        const float base = pre + (v - s);       // exclusive prefix before this thread's 4
        const float p0 = base + m.x;
        const float p1 = p0 + m.y;
        const float p2 = p1 + m.z;
        const float p3 = p2 + m.w;
        const float4 w4 = wt4[idx];
        const float fr0 = p0 - floorf(p0), fr1 = p1 - floorf(p1);
        const float fr2 = p2 - floorf(p2), fr3 = p3 - floorf(p3);
        c14[idx] = make_float4((1.f - fr0) * w4.x, (1.f - fr1) * w4.y,
                               (1.f - fr2) * w4.z, (1.f - fr3) * w4.w);
        c24[idx] = make_float4(fr0 * w4.x, fr1 * w4.y, fr2 * w4.z, fr3 * w4.w);
        // integer crossings in (base, p3]: lower_bound index for each
        {
            int lf = (int)floorf(base) + 1;
            const int lfe = (int)floorf(p3);
            const int tbase = idx << 2;
            for (; lf <= lfe; ++lf) {
                const float lff = (float)lf;
                int t = tbase;
                if (p0 >= lff) { }
                else if (p1 >= lff) t += 1;
                else if (p2 >= lff) t += 2;
                else t += 3;
                if (lf + 1 < BSTRIDE) bb[lf + 1] = t;
            }
        }
        if (chunk == 1 && tid == 1023) lens[b] = floorf(p3) + 2.0f;
        carry += tot;
        __syncthreads();
    }
}

// ---------------- Kernel 3: fused GLU-features + CIF pooling + zero-fill ----------------
static constexpr int LTILE = 32;
static constexpr int CHK = 256;
static constexpr int NPOOLX = (LFULL + LTILE - 1) / LTILE;  // 257

__global__ __launch_bounds__(256) void k_pool(
    const float* __restrict__ x,
    const float* __restrict__ cw,
    const float* __restrict__ bng, const float* __restrict__ bnb,
    const float* __restrict__ bnm, const float* __restrict__ bnv,
    const float* __restrict__ coef1, const float* __restrict__ coef2,
    const int* __restrict__ bnd, const float* __restrict__ lens,
    float* __restrict__ xevs)
{
    __shared__ float out_lds[256 * 33];     // [c][li], stride 33 (conflict-free)
    __shared__ float4 xl4[68];              // x window, chunk-staged (CHK+12 floats)
    __shared__ float4 c1l4[CHK / 4], c2l4[CHK / 4];
    __shared__ int lbs[LTILE + 2];
    float* xl = (float*)xl4;
    float* c1l = (float*)c1l4;
    float* c2l = (float*)c2l4;

    const int tid = threadIdx.x;
    const int b = blockIdx.y;

    if (blockIdx.x >= NPOOLX) {   // zero role: stream zeros over l >= ceil16(lens[b])
        const int zx = blockIdx.x - NPOOLX;       // 0..63, 4 rows each
        const int zs = (((int)lens[b]) + 15) & ~15;
        if (zs >= LFULL) return;
        const int n4 = (LFULL - zs) >> 2;
        for (int r = 0; r < 4; ++r) {
            float* row = &xevs[((size_t)(b * 256 + zx * 4 + r)) * LFULL + zs];
            for (int i = tid; i < n4; i += 256) nt_store4(row + 4 * i, 0.f, 0.f, 0.f, 0.f);
        }
        return;
    }

    const int l0 = blockIdx.x * LTILE;
    const int LTa = min(LTILE, LFULL - l0);

    if (tid < LTa + 2) lbs[tid] = bnd[b * BSTRIDE + l0 + tid];  // lf = l0-1+tid
    __syncthreads();

    const int t_lo = lbs[0];
    const int t_hi = lbs[LTa + 1];
    if (t_lo >= t_hi) return;   // inactive tile: zero role covers it

    const size_t rowbase = (size_t)b * 256 * LFULL + l0;

    // zero own row (columns never emitted must read 0)
#pragma unroll
    for (int li = 0; li < 33; ++li) out_lds[tid * 33 + li] = 0.f;

    const int c = tid;
    float wa[9], wg[9];
#pragma unroll
    for (int k = 0; k < 9; ++k) { wa[k] = cw[c * 9 + k]; wg[k] = cw[(c + 256) * 9 + k]; }
    const float sa = bng[c] * rsqrtf(bnv[c] + 1e-3f);
    const float sha = bnb[c] - bnm[c] * sa;
    const float sg = bng[c + 256] * rsqrtf(bnv[c + 256] + 1e-3f);
    const float shg = bnb[c + 256] - bnm[c + 256] * sg;

    const float* xg = &x[b * TT];
    const float* c1g = &coef1[b * TT];
    const float* c2g = &coef2[b * TT];

    float accA = 0.f, accB = 0.f;   // accA: column j-1, accB: column j
    int j = 0;
    int nb = lbs[1];

    for (int cs = t_lo; cs < t_hi; cs += CHK) {
        const int ce = min(cs + CHK, t_hi);
        const int len = ce - cs;
        __syncthreads();           // previous chunk fully consumed
        for (int idx = tid; idx < len + 12; idx += 256) {
            int id = cs - 4 + idx;
            xl[idx] = (id >= 0 && id < TT) ? xg[id] : 0.f;
        }
        if (tid < len) { c1l[tid] = c1g[cs + tid]; c2l[tid] = c2g[cs + tid]; }
        __syncthreads();

        const int len4 = len >> 2;
        for (int g = 0; g < len4; ++g) {
            float4 A = xl4[g], Bq = xl4[g + 1], Cq = xl4[g + 2];
            float w[12] = {A.x, A.y, A.z, A.w, Bq.x, Bq.y, Bq.z, Bq.w, Cq.x, Cq.y, Cq.z, Cq.w};
            float f[4];
#pragma unroll
            for (int i = 0; i < 4; ++i) {
                float s0 = 0.f, s1 = 0.f;
#pragma unroll
                for (int k = 0; k < 9; ++k) { s0 = fmaf(wa[k], w[i + k], s0); s1 = fmaf(wg[k], w[i + k], s1); }
                const float av = fmaf(s0, sa, sha);
                const float gv = fmaf(s1, sg, shg);
                f[i] = av * sig_(gv);
            }
            float4 c1v = c1l4[g], c2v = c2l4[g];
            const float c1a[4] = {c1v.x, c1v.y, c1v.z, c1v.w};
            const float c2a[4] = {c2v.x, c2v.y, c2v.z, c2v.w};
            const int tb = cs + (g << 2);
#pragma unroll
            for (int i = 0; i < 4; ++i) {
                const int t = tb + i;
                while (t >= nb) {   // segment crossing(s)
                    int li = j - 1;
                    if (li >= 0 && li < LTa) out_lds[c * 33 + li] = accA;
                    accA = accB; accB = 0.f;
                    ++j;
                    nb = lbs[j + 1];
                }
                accA = fmaf(c1a[i], f[i], accA);
                accB = fmaf(c2a[i], f[i], accB);
            }
        }
        // tail (len not multiple of 4)
        for (int t = cs + (len4 << 2); t < ce; ++t) {
            const int il = t - cs;
            float s0 = 0.f, s1 = 0.f;
#pragma unroll
            for (int k = 0; k < 9; ++k) { float xv = xl[il + k]; s0 = fmaf(wa[k], xv, s0); s1 = fmaf(wg[k], xv, s1); }
            const float av = fmaf(s0, sa, sha);
            const float gv = fmaf(s1, sg, shg);
            const float f0 = av * sig_(gv);
            while (t >= nb) {
                int li = j - 1;
                if (li >= 0 && li < LTa) out_lds[c * 33 + li] = accA;
                accA = accB; accB = 0.f;
                ++j;
                nb = lbs[j + 1];
            }
            accA = fmaf(c1l[il], f0, accA);
            accB = fmaf(c2l[il], f0, accB);
        }
    }
    {   // trailing emit
        int li = j - 1;
        if (li >= 0 && li < LTa) out_lds[c * 33 + li] = accA;
    }
    __syncthreads();

#pragma unroll
    for (int it = 0; it < 8; ++it) {
        int idx4 = it * 256 + tid;
        int cc = idx4 >> 3, q = (idx4 & 7) << 2;
        if (q < LTa) {
            nt_store4(&xevs[rowbase + (size_t)cc * LFULL + q],
                      out_lds[cc * 33 + q + 0], out_lds[cc * 33 + q + 1],
                      out_lds[cc * 33 + q + 2], out_lds[cc * 33 + q + 3]);
        }
    }
}

extern "C" void kernel_launch(void* const* d_in, const int* in_sizes, int n_in,
                              void* d_out, int out_size, void* d_ws, size_t ws_size,
                              hipStream_t stream) {
    (void)in_sizes; (void)n_in; (void)out_size; (void)ws_size;
    const float* x      = (const float*)d_in[0];
    const float* conv_w = (const float*)d_in[1];
    const float* bn_g   = (const float*)d_in[2];
    const float* bn_b   = (const float*)d_in[3];
    const float* bn_m   = (const float*)d_in[4];
    const float* bn_v   = (const float*)d_in[5];
    const float* p1_w   = (const float*)d_in[6];
    const float* p1_b   = (const float*)d_in[7];
    const float* pbn1_g = (const float*)d_in[8];
    const float* pbn1_b = (const float*)d_in[9];
    const float* pbn1_m = (const float*)d_in[10];
    const float* pbn1_v = (const float*)d_in[11];
    const float* p2_w   = (const float*)d_in[12];
    const float* p2_b   = (const float*)d_in[13];
    const float* pbn2_g = (const float*)d_in[14];
    const float* pbn2_b = (const float*)d_in[15];
    const float* pbn2_m = (const float*)d_in[16];
    const float* pbn2_v = (const float*)d_in[17];
    const float* p3_w   = (const float*)d_in[18];
    const float* p3_b   = (const float*)d_in[19];
    const float* nm     = (const float*)d_in[20];

    float* out = (float*)d_out;
    float* ws  = (float*)d_ws;
    float* v     = ws + V_OFF;
    float* moves = ws + MOVES_OFF;
    float* coef1 = ws + C1_OFF;
    float* coef2 = ws + C2_OFF;
    int*   bnd   = (int*)(ws + BND_OFF);
    float* xevs  = out + XE_OFF;
    float* lens  = out + LENS_OFF;
    float* bmv   = out + BM_OFF;
    float* wts   = out + WT_OFF;

    k_conv12<<<dim3(32, 16, 2), 256, 0, stream>>>(
        x, p1_w, p1_b, pbn1_g, pbn1_b, pbn1_m, pbn1_v,
        p2_w, p2_b, pbn2_g, pbn2_b, pbn2_m, pbn2_v, v);
    k_conv3<<<dim3(32, 16), 256, 0, stream>>>(v, p3_w, p3_b, nm, wts, bmv, moves);
    k_scan<<<16, 1024, 0, stream>>>(moves, wts, coef1, coef2, bnd, lens);
    k_pool<<<dim3(NPOOLX + 64, 16), 256, 0, stream>>>(
        x, conv_w, bn_g, bn_b, bn_m, bn_v, coef1, coef2, bnd, lens, xevs);
}